// Round 10
// baseline (649.607 us; speedup 1.0000x reference)
//
#include <hip/hip_runtime.h>
#include <math.h>

#define DIMC 192
#define C3 576
#define NHEADS 8
#define CDh 24
#define HWN 16384
#define WIDTH 128
#define NBATCH 8

typedef __attribute__((ext_vector_type(8))) short short8;
typedef __attribute__((ext_vector_type(4))) float f32x4;

__device__ __forceinline__ ushort f2bf(float f) {
    uint u = __float_as_uint(f);
    u += 0x7fff + ((u >> 16) & 1);
    return (ushort)(u >> 16);
}
__device__ __forceinline__ float bf2f(ushort h) {
    return __uint_as_float(((uint)h) << 16);
}

// ============ K0: split W_qkv -> bf16 hi/lo ============
__global__ void k0_prep(const float* __restrict__ W, ushort* __restrict__ Wh,
                        ushort* __restrict__ Wl, int n) {
    int i = blockIdx.x * 256 + threadIdx.x;
    if (i < n) {
        float w = W[i];
        ushort h = f2bf(w);
        Wh[i] = h;
        Wl[i] = f2bf(w - bf2f(h));
    }
}

// ============ KGX9: qkv = W @ x + b via split-bf16 MFMA; x fp32 staged+split in LDS ============
// grid (256 n-tiles of 64 px, 1, NZ), block 256 (4 waves; wave = 144 rows x 64 px).
// nt streaming stores for qkv (transient data; probes the write-amplification mechanism).
__global__ __launch_bounds__(256, 3) void kgx9(const float* __restrict__ x,
                                               const ushort* __restrict__ Wh,
                                               const ushort* __restrict__ Wl,
                                               const float* __restrict__ bias,
                                               float* __restrict__ qkv, long qkv_zs) {
    __shared__ ushort smem[2 * 64 * 200];  // B-stage hi/lo; reused as f32 epilogue buf
    ushort* BsH = smem;
    ushort* BsL = smem + 64 * 200;
    const int z = blockIdx.z;
    const float* xb = x + (size_t)z * DIMC * HWN;
    const int n0 = blockIdx.x * 64;
    const int tid = threadIdx.x;
#pragma unroll
    for (int it = 0; it < 12; it++) {
        int idx = tid + it * 256;
        int ch = idx >> 4, q = idx & 15;
        f32x4 v = *(const f32x4*)&xb[(size_t)ch * HWN + n0 + q * 4];
#pragma unroll
        for (int p = 0; p < 4; p++) {
            ushort hb = f2bf(v[p]);
            BsH[(q * 4 + p) * 200 + ch] = hb;
            BsL[(q * 4 + p) * 200 + ch] = f2bf(v[p] - bf2f(hb));
        }
    }
    __syncthreads();
    const int wid = tid >> 6, lane = tid & 63;
    const int lr = lane & 15, lk = lane >> 4;
    const int mb = wid * 144;
    float* oz = qkv + (size_t)z * qkv_zs;
    f32x4 acc[9][4];
#pragma unroll
    for (int i = 0; i < 9; i++)
#pragma unroll
        for (int j = 0; j < 4; j++) acc[i][j] = (f32x4)0.f;

    for (int kc6 = 0; kc6 < 6; kc6++) {
        short8 bh[4], bl[4];
#pragma unroll
        for (int j = 0; j < 4; j++) {
            int ad = (j * 16 + lr) * 200 + kc6 * 32 + lk * 8;
            bh[j] = *(const short8*)&BsH[ad];
            bl[j] = *(const short8*)&BsL[ad];
        }
#pragma unroll
        for (int i = 0; i < 9; i++) {
            size_t ao = (size_t)(mb + i * 16 + lr) * DIMC + kc6 * 32 + lk * 8;
            const short8 ah = *(const short8*)&Wh[ao];
            const short8 al = *(const short8*)&Wl[ao];
#pragma unroll
            for (int j = 0; j < 4; j++) {
                acc[i][j] = __builtin_amdgcn_mfma_f32_16x16x32_bf16(ah, bh[j], acc[i][j], 0, 0, 0);
                acc[i][j] = __builtin_amdgcn_mfma_f32_16x16x32_bf16(ah, bl[j], acc[i][j], 0, 0, 0);
                acc[i][j] = __builtin_amdgcn_mfma_f32_16x16x32_bf16(al, bh[j], acc[i][j], 0, 0, 0);
            }
        }
    }
    __syncthreads();  // all waves done reading BsH/BsL -> reuse as epilogue staging
    float* epsb = (float*)smem + wid * (2 * 1056);  // per-wave double buffer [2][16][66]
#pragma unroll
    for (int i = 0; i < 9; i++) {
        float* eps = epsb + (i & 1) * 1056;
        int rb = mb + i * 16;
#pragma unroll
        for (int j = 0; j < 4; j++)
#pragma unroll
            for (int r = 0; r < 4; r++)
                eps[(lk * 4 + r) * 66 + j * 16 + lr] = acc[i][j][r] + bias[rb + lk * 4 + r];
#pragma unroll
        for (int s = 0; s < 4; s++) {
            int rl = s * 4 + (lane >> 4);
            int c4 = (lane & 15) * 4;
            f32x4 v = *(const f32x4*)&eps[rl * 66 + c4];
            __builtin_nontemporal_store(v, (f32x4*)&oz[(size_t)(rb + rl) * HWN + n0 + c4]);
        }
    }
}

// ============ KG3F: y = M_b @ v + b_proj, IN-PLACE on d_out; v fp32 staged+split in LDS ============
// grid (256 n-tiles of 64, 8 b), block 256 (4 waves; wave = 48 rows x 64 px).
__global__ __launch_bounds__(256, 3) void kg3f(float* __restrict__ vy,
                                               const ushort* __restrict__ Mh,
                                               const ushort* __restrict__ Ml,
                                               const float* __restrict__ bias) {
    __shared__ ushort smem[2 * 64 * 200];
    ushort* BsH = smem;
    ushort* BsL = smem + 64 * 200;
    const int z = blockIdx.y;
    float* vb = vy + (size_t)z * DIMC * HWN;
    const int n0 = blockIdx.x * 64;
    const int tid = threadIdx.x;
#pragma unroll
    for (int it = 0; it < 12; it++) {
        int idx = tid + it * 256;
        int ch = idx >> 4, q = idx & 15;
        f32x4 v = *(const f32x4*)&vb[(size_t)ch * HWN + n0 + q * 4];
#pragma unroll
        for (int p = 0; p < 4; p++) {
            ushort hb = f2bf(v[p]);
            BsH[(q * 4 + p) * 200 + ch] = hb;
            BsL[(q * 4 + p) * 200 + ch] = f2bf(v[p] - bf2f(hb));
        }
    }
    __syncthreads();
    const int wid = tid >> 6, lane = tid & 63;
    const int lr = lane & 15, lk = lane >> 4;
    const int mb = wid * 48;
    const ushort* Azh = Mh + (size_t)z * DIMC * DIMC;
    const ushort* Azl = Ml + (size_t)z * DIMC * DIMC;
    f32x4 acc[3][4];
#pragma unroll
    for (int i = 0; i < 3; i++)
#pragma unroll
        for (int j = 0; j < 4; j++) acc[i][j] = (f32x4)0.f;

    for (int kc6 = 0; kc6 < 6; kc6++) {
        short8 bh[4], bl[4];
#pragma unroll
        for (int j = 0; j < 4; j++) {
            int ad = (j * 16 + lr) * 200 + kc6 * 32 + lk * 8;
            bh[j] = *(const short8*)&BsH[ad];
            bl[j] = *(const short8*)&BsL[ad];
        }
#pragma unroll
        for (int i = 0; i < 3; i++) {
            size_t ao = (size_t)(mb + i * 16 + lr) * DIMC + kc6 * 32 + lk * 8;
            const short8 ah = *(const short8*)&Azh[ao];
            const short8 al = *(const short8*)&Azl[ao];
#pragma unroll
            for (int j = 0; j < 4; j++) {
                acc[i][j] = __builtin_amdgcn_mfma_f32_16x16x32_bf16(ah, bh[j], acc[i][j], 0, 0, 0);
                acc[i][j] = __builtin_amdgcn_mfma_f32_16x16x32_bf16(ah, bl[j], acc[i][j], 0, 0, 0);
                acc[i][j] = __builtin_amdgcn_mfma_f32_16x16x32_bf16(al, bh[j], acc[i][j], 0, 0, 0);
            }
        }
    }
    __syncthreads();  // all v reads done (LDS holds v); in-place writes + LDS reuse safe
    float* epsb = (float*)smem + wid * (2 * 1056);
#pragma unroll
    for (int i = 0; i < 3; i++) {
        float* eps = epsb + (i & 1) * 1056;
        int rb = mb + i * 16;
#pragma unroll
        for (int j = 0; j < 4; j++)
#pragma unroll
            for (int r = 0; r < 4; r++)
                eps[(lk * 4 + r) * 66 + j * 16 + lr] = acc[i][j][r] + bias[rb + lk * 4 + r];
#pragma unroll
        for (int s = 0; s < 4; s++) {
            int rl = s * 4 + (lane >> 4);
            int c4 = (lane & 15) * 4;
            f32x4 v = *(const f32x4*)&eps[rl * 66 + c4];
            *(f32x4*)&vb[(size_t)(rb + rl) * HWN + n0 + c4] = v;
        }
    }
}

// ============ K2: depthwise 3x3 + Gram/sumsq partials; v -> fp32 d_out ============
__global__ __launch_bounds__(1024, 4) void k2_dw(const float* __restrict__ qkv0, long qkv_zs,
                                                 const float* __restrict__ wdw,
                                                 const float* __restrict__ bdw,
                                                 float* __restrict__ vout,
                                                 float* __restrict__ part, int b0) {
    __shared__ float stage[2 * 6336];   // [2][8][6][132]
    __shared__ float qks[48 * 520];     // [qk ch][512 px + pad], fp32
    const int b = b0 + blockIdx.z;
    const float* qkv = qkv0 + (size_t)blockIdx.z * qkv_zs;
    const int stripe = blockIdx.x, h = blockIdx.y;
    const int tid = threadIdx.x;
    const int r0 = stripe * 4;

    const int col4 = (tid & 31) * 4;
    const int orow = (tid >> 5) & 3;
    const int cc = tid >> 7;  // 0..7

    auto stage_load = [&](int chunk, int buf) {
        const int g = chunk / 3, cb = (chunk % 3) * 8;
        float* sb = stage + buf * 6336;
#pragma unroll
        for (int f = tid; f < 1536; f += 1024) {
            int fc = f / 192, rem = f - fc * 192;
            int rl = rem >> 5, c4 = rem & 31;
            int gr = r0 - 1 + rl;
            int ch = g * DIMC + h * CDh + cb + fc;
            float4 v = make_float4(0.f, 0.f, 0.f, 0.f);
            if (gr >= 0 && gr < 128)
                v = *(const float4*)&qkv[(size_t)ch * HWN + gr * WIDTH + c4 * 4];
            *(float4*)&sb[(fc * 6 + rl) * 132 + c4 * 4] = v;
        }
    };

    stage_load(0, 0);
    __syncthreads();
    for (int chunk = 0; chunk < 9; chunk++) {
        const int buf = chunk & 1;
        if (chunk < 8) stage_load(chunk + 1, buf ^ 1);
        const int g = chunk / 3, cb = (chunk % 3) * 8;
        const float* sb = stage + buf * 6336;
        const int ch = g * DIMC + h * CDh + cb + cc;
        float wr[9];
#pragma unroll
        for (int t = 0; t < 9; t++) wr[t] = wdw[ch * 9 + t];
        float bsv = bdw[ch];
        float a0 = bsv, a1 = bsv, a2 = bsv, a3 = bsv;
#pragma unroll
        for (int dr = 0; dr < 3; dr++) {
            const float* row = &sb[(cc * 6 + orow + dr) * 132];
            f32x4 cen = *(const f32x4*)&row[col4];
            f32x4 lf4 = (col4 > 0) ? *(const f32x4*)&row[col4 - 4] : (f32x4)0.f;
            f32x4 rt4 = (col4 < 124) ? *(const f32x4*)&row[col4 + 4] : (f32x4)0.f;
            float left = lf4[3], right = rt4[0];
            float wA = wr[dr * 3 + 0], wB = wr[dr * 3 + 1], wC = wr[dr * 3 + 2];
            a0 = fmaf(left, wA, fmaf(cen[0], wB, fmaf(cen[1], wC, a0)));
            a1 = fmaf(cen[0], wA, fmaf(cen[1], wB, fmaf(cen[2], wC, a1)));
            a2 = fmaf(cen[1], wA, fmaf(cen[2], wB, fmaf(cen[3], wC, a2)));
            a3 = fmaf(cen[2], wA, fmaf(cen[3], wB, fmaf(right, wC, a3)));
        }
        if (g < 2) {
            float4 o4 = {a0, a1, a2, a3};
            *(float4*)&qks[(g * CDh + cb + cc) * 520 + orow * 128 + col4] = o4;
        } else {
            f32x4 o4 = {a0, a1, a2, a3};
            __builtin_nontemporal_store(
                o4, (f32x4*)&vout[((size_t)b * DIMC + h * CDh + cb + cc) * HWN +
                                  (size_t)(r0 + orow) * WIDTH + col4]);
        }
        __syncthreads();
    }

    const int tc = tid & 3, td = (tid >> 2) & 3, tp = tid >> 4;
    float ga[6][6];
#pragma unroll
    for (int i = 0; i < 6; i++)
#pragma unroll
        for (int j = 0; j < 6; j++) ga[i][j] = 0.f;
#pragma unroll
    for (int s = 0; s < 2; s++) {
        int px = tp * 8 + s * 4;
        f32x4 qv[6], kv[6];
#pragma unroll
        for (int i = 0; i < 6; i++) qv[i] = *(const f32x4*)&qks[(tc * 6 + i) * 520 + px];
#pragma unroll
        for (int j = 0; j < 6; j++) kv[j] = *(const f32x4*)&qks[(24 + td * 6 + j) * 520 + px];
#pragma unroll
        for (int i = 0; i < 6; i++)
#pragma unroll
            for (int j = 0; j < 6; j++) {
                ga[i][j] = fmaf(qv[i][0], kv[j][0], ga[i][j]);
                ga[i][j] = fmaf(qv[i][1], kv[j][1], ga[i][j]);
                ga[i][j] = fmaf(qv[i][2], kv[j][2], ga[i][j]);
                ga[i][j] = fmaf(qv[i][3], kv[j][3], ga[i][j]);
            }
    }
#pragma unroll
    for (int i = 0; i < 6; i++)
#pragma unroll
        for (int j = 0; j < 6; j++) {
            float v = ga[i][j];
            v += __shfl_xor(v, 16, 64);
            v += __shfl_xor(v, 32, 64);
            ga[i][j] = v;
        }
    float nv = 0.f;
    int nch = 0, npg = 0;
    if (tid < 768) {
        npg = tid / 48;
        nch = tid - npg * 48;
#pragma unroll
        for (int s = 0; s < 8; s++) {
            f32x4 v = *(const f32x4*)&qks[nch * 520 + npg * 32 + s * 4];
            nv = fmaf(v[0], v[0], nv);
            nv = fmaf(v[1], v[1], nv);
            nv = fmaf(v[2], v[2], nv);
            nv = fmaf(v[3], v[3], nv);
        }
    }
    __syncthreads();
    float* gscr = qks;  // [16][624]
    const int wave = tid >> 6;
    if ((tid & 63) < 16) {
#pragma unroll
        for (int i = 0; i < 6; i++)
#pragma unroll
            for (int j = 0; j < 6; j++)
                gscr[wave * 624 + (tc * 6 + i) * 24 + (td * 6 + j)] = ga[i][j];
    }
    if (tid < 768) gscr[npg * 624 + 576 + nch] = nv;
    __syncthreads();
    if (tid < 624) {
        float s = 0.f;
#pragma unroll
        for (int w2 = 0; w2 < 16; w2++) s += gscr[w2 * 624 + tid];
        part[((size_t)(b * NHEADS + h) * 64 + stripe) * 624 + tid] = s;  // coalesced
    }
}

// ============ K34: reduce partials + attn + 4 top-k softmaxes -> A_eff ============
__global__ void k34_attn(const float* __restrict__ part, const float* __restrict__ temp,
                         const float* __restrict__ a1, const float* __restrict__ a2,
                         const float* __restrict__ a3, const float* __restrict__ a4,
                         float* __restrict__ Aeff) {
    __shared__ float gbuf[624];
    int bh = blockIdx.x;
    int h = bh & 7;
    int tid = threadIdx.x;
    for (int ti = tid; ti < 624; ti += 256) {
        float s = 0.f;
        const float* p = part + (size_t)bh * 64 * 624 + ti;
#pragma unroll 4
        for (int st = 0; st < 64; st++) s += p[st * 624];
        gbuf[ti] = s;
    }
    __syncthreads();
    int r = tid;
    if (r >= CDh) return;
    float t = temp[h];
    float aw[4] = {a1[0], a2[0], a3[0], a4[0]};
    const int kks[4] = {12, 16, 18, 19};
    float qn = fmaxf(sqrtf(gbuf[576 + r]), 1e-12f);
    float av[24];
    for (int d = 0; d < 24; d++) {
        float kn = fmaxf(sqrtf(gbuf[600 + d]), 1e-12f);
        av[d] = gbuf[r * 24 + d] / (qn * kn) * t;
    }
    int rank[24];
    float m = -1e30f;
    for (int d = 0; d < 24; d++) {
        int rk = 0;
        for (int e = 0; e < 24; e++)
            rk += (av[e] > av[d]) || (av[e] == av[d] && e < d);
        rank[d] = rk;
        m = fmaxf(m, av[d]);
    }
    float ex[24], outv[24];
    for (int d = 0; d < 24; d++) { ex[d] = expf(av[d] - m); outv[d] = 0.f; }
    for (int i = 0; i < 4; i++) {
        float Z = 0.f;
        for (int d = 0; d < 24; d++) if (rank[d] < kks[i]) Z += ex[d];
        float inv = aw[i] / Z;
        for (int d = 0; d < 24; d++) if (rank[d] < kks[i]) outv[d] += ex[d] * inv;
    }
    for (int d = 0; d < 24; d++) Aeff[(bh * 24 + r) * 24 + d] = outv[d];
}

// ============ K4b: M_b = W_proj @ blockdiag(A_eff) -> bf16 hi/lo ============
__global__ void k4b_mmat(const float* __restrict__ Wp, const float* __restrict__ Aeff,
                         ushort* __restrict__ Mh, ushort* __restrict__ Ml) {
    int b = blockIdx.x;
    int e0 = blockIdx.y * 6144;
    for (int e = e0 + threadIdx.x; e < e0 + 6144; e += 256) {
        int o = e / DIMC, j = e % DIMC;
        int h = j / CDh, d = j % CDh;
        const float* wrow = Wp + o * DIMC + h * CDh;
        const float* acol = Aeff + (size_t)((b * NHEADS + h) * CDh) * CDh + d;
        float s = 0.f;
        for (int c = 0; c < CDh; c++) s = fmaf(wrow[c], acol[c * CDh], s);
        size_t idx = ((size_t)b * DIMC + o) * DIMC + j;
        ushort hb = f2bf(s);
        Mh[idx] = hb;
        Ml[idx] = f2bf(s - bf2f(hb));
    }
}

extern "C" void kernel_launch(void* const* d_in, const int* in_sizes, int n_in,
                              void* d_out, int out_size, void* d_ws, size_t ws_size,
                              hipStream_t stream) {
    const float* x     = (const float*)d_in[0];
    const float* wqkv  = (const float*)d_in[1];
    const float* bqkv  = (const float*)d_in[2];
    const float* wdw   = (const float*)d_in[3];
    const float* bdw   = (const float*)d_in[4];
    const float* wproj = (const float*)d_in[5];
    const float* bproj = (const float*)d_in[6];
    const float* temp  = (const float*)d_in[7];
    const float* a1    = (const float*)d_in[8];
    const float* a2    = (const float*)d_in[9];
    const float* a3    = (const float*)d_in[10];
    const float* a4    = (const float*)d_in[11];
    float* out = (float*)d_out;

    float* ws = (float*)d_ws;
    const size_t fl_part = (size_t)64 * 64 * 624;
    const size_t fl_A    = (size_t)64 * 576;
    const size_t fl_M    = (size_t)NBATCH * DIMC * DIMC / 2;
    const size_t fl_W    = (size_t)C3 * DIMC / 2;
    const size_t fl_qkv1 = (size_t)C3 * HWN;
    const size_t base_fl = fl_part + fl_A + 2 * fl_M + 2 * fl_W;

    auto need = [&](int nzz) -> size_t {
        return (base_fl + (size_t)nzz * fl_qkv1) * sizeof(float);
    };
    int nz = 1;
    if (ws_size >= need(8))      nz = 8;
    else if (ws_size >= need(4)) nz = 4;
    else if (ws_size >= need(2)) nz = 2;

    size_t o = 0;
    float* part = ws + o; o += fl_part;
    float* Aeff = ws + o; o += fl_A;
    ushort* Mh  = (ushort*)(ws + o); o += fl_M;
    ushort* Ml  = (ushort*)(ws + o); o += fl_M;
    ushort* Wh  = (ushort*)(ws + o); o += fl_W;
    ushort* Wl  = (ushort*)(ws + o); o += fl_W;
    float* qkv  = ws + o;

    const long qkv_zs = (long)fl_qkv1;

    k0_prep<<<(C3 * DIMC + 255) / 256, 256, 0, stream>>>(wqkv, Wh, Wl, C3 * DIMC);

    for (int b0 = 0; b0 < NBATCH; b0 += nz) {
        kgx9<<<dim3(256, 1, nz), 256, 0, stream>>>(x + (size_t)b0 * DIMC * HWN,
                                                   Wh, Wl, bqkv, qkv, qkv_zs);
        k2_dw<<<dim3(32, 8, nz), 1024, 0, stream>>>(qkv, qkv_zs, wdw, bdw, out, part, b0);
    }
    k34_attn<<<64, 256, 0, stream>>>(part, temp, a1, a2, a3, a4, Aeff);
    k4b_mmat<<<dim3(8, 6), 256, 0, stream>>>(wproj, Aeff, Mh, Ml);
    kg3f<<<dim3(256, 8), 256, 0, stream>>>(out, Mh, Ml, bproj);
}

// Round 11
// 648.756 us; speedup vs baseline: 1.0013x; 1.0013x over previous
//
#include <hip/hip_runtime.h>
#include <math.h>

#define DIMC 192
#define C3 576
#define NHEADS 8
#define CDh 24
#define HWN 16384
#define WIDTH 128
#define NBATCH 8

typedef __attribute__((ext_vector_type(8))) short short8;
typedef __attribute__((ext_vector_type(4))) float f32x4;

__device__ __forceinline__ ushort f2bf(float f) {
    uint u = __float_as_uint(f);
    u += 0x7fff + ((u >> 16) & 1);
    return (ushort)(u >> 16);
}
__device__ __forceinline__ float bf2f(ushort h) {
    return __uint_as_float(((uint)h) << 16);
}

// ============ K0: split W_qkv -> bf16 hi/lo ============
__global__ void k0_prep(const float* __restrict__ W, ushort* __restrict__ Wh,
                        ushort* __restrict__ Wl, int n) {
    int i = blockIdx.x * 256 + threadIdx.x;
    if (i < n) {
        float w = W[i];
        ushort h = f2bf(w);
        Wh[i] = h;
        Wl[i] = f2bf(w - bf2f(h));
    }
}

// ============ KGX9: qkv = W @ x + b via split-bf16 MFMA; x fp32 staged+split in LDS ============
// grid (256 n-tiles of 64 px, 1, NZ), block 256 (4 waves; wave = 144 rows x 64 px).
__global__ __launch_bounds__(256, 3) void kgx9(const float* __restrict__ x,
                                               const ushort* __restrict__ Wh,
                                               const ushort* __restrict__ Wl,
                                               const float* __restrict__ bias,
                                               float* __restrict__ qkv, long qkv_zs) {
    __shared__ ushort smem[2 * 64 * 200];  // B-stage hi/lo; reused as f32 epilogue buf
    ushort* BsH = smem;
    ushort* BsL = smem + 64 * 200;
    const int z = blockIdx.z;
    const float* xb = x + (size_t)z * DIMC * HWN;
    const int n0 = blockIdx.x * 64;
    const int tid = threadIdx.x;
#pragma unroll
    for (int it = 0; it < 12; it++) {
        int idx = tid + it * 256;
        int ch = idx >> 4, q = idx & 15;
        f32x4 v = *(const f32x4*)&xb[(size_t)ch * HWN + n0 + q * 4];
#pragma unroll
        for (int p = 0; p < 4; p++) {
            ushort hb = f2bf(v[p]);
            BsH[(q * 4 + p) * 200 + ch] = hb;
            BsL[(q * 4 + p) * 200 + ch] = f2bf(v[p] - bf2f(hb));
        }
    }
    __syncthreads();
    const int wid = tid >> 6, lane = tid & 63;
    const int lr = lane & 15, lk = lane >> 4;
    const int mb = wid * 144;
    float* oz = qkv + (size_t)z * qkv_zs;
    f32x4 acc[9][4];
#pragma unroll
    for (int i = 0; i < 9; i++)
#pragma unroll
        for (int j = 0; j < 4; j++) acc[i][j] = (f32x4)0.f;

    for (int kc6 = 0; kc6 < 6; kc6++) {
        short8 bh[4], bl[4];
#pragma unroll
        for (int j = 0; j < 4; j++) {
            int ad = (j * 16 + lr) * 200 + kc6 * 32 + lk * 8;
            bh[j] = *(const short8*)&BsH[ad];
            bl[j] = *(const short8*)&BsL[ad];
        }
#pragma unroll
        for (int i = 0; i < 9; i++) {
            size_t ao = (size_t)(mb + i * 16 + lr) * DIMC + kc6 * 32 + lk * 8;
            const short8 ah = *(const short8*)&Wh[ao];
            const short8 al = *(const short8*)&Wl[ao];
#pragma unroll
            for (int j = 0; j < 4; j++) {
                acc[i][j] = __builtin_amdgcn_mfma_f32_16x16x32_bf16(ah, bh[j], acc[i][j], 0, 0, 0);
                acc[i][j] = __builtin_amdgcn_mfma_f32_16x16x32_bf16(ah, bl[j], acc[i][j], 0, 0, 0);
                acc[i][j] = __builtin_amdgcn_mfma_f32_16x16x32_bf16(al, bh[j], acc[i][j], 0, 0, 0);
            }
        }
    }
    __syncthreads();  // all waves done reading BsH/BsL -> reuse as epilogue staging
    float* epsb = (float*)smem + wid * (2 * 1056);  // per-wave double buffer [2][16][66]
#pragma unroll
    for (int i = 0; i < 9; i++) {
        float* eps = epsb + (i & 1) * 1056;
        int rb = mb + i * 16;
#pragma unroll
        for (int j = 0; j < 4; j++)
#pragma unroll
            for (int r = 0; r < 4; r++)
                eps[(lk * 4 + r) * 66 + j * 16 + lr] = acc[i][j][r] + bias[rb + lk * 4 + r];
#pragma unroll
        for (int s = 0; s < 4; s++) {
            int rl = s * 4 + (lane >> 4);
            int c4 = (lane & 15) * 4;
            f32x4 v = *(const f32x4*)&eps[rl * 66 + c4];
            *(f32x4*)&oz[(size_t)(rb + rl) * HWN + n0 + c4] = v;
        }
    }
}

// ============ KG3F: y = M_b @ v + b_proj, IN-PLACE on d_out; v fp32 staged+split in LDS ============
// grid (256 n-tiles of 64, 8 b), block 256 (4 waves; wave = 48 rows x 64 px).
__global__ __launch_bounds__(256, 3) void kg3f(float* __restrict__ vy,
                                               const ushort* __restrict__ Mh,
                                               const ushort* __restrict__ Ml,
                                               const float* __restrict__ bias) {
    __shared__ ushort smem[2 * 64 * 200];
    ushort* BsH = smem;
    ushort* BsL = smem + 64 * 200;
    const int z = blockIdx.y;
    float* vb = vy + (size_t)z * DIMC * HWN;
    const int n0 = blockIdx.x * 64;
    const int tid = threadIdx.x;
#pragma unroll
    for (int it = 0; it < 12; it++) {
        int idx = tid + it * 256;
        int ch = idx >> 4, q = idx & 15;
        f32x4 v = *(const f32x4*)&vb[(size_t)ch * HWN + n0 + q * 4];
#pragma unroll
        for (int p = 0; p < 4; p++) {
            ushort hb = f2bf(v[p]);
            BsH[(q * 4 + p) * 200 + ch] = hb;
            BsL[(q * 4 + p) * 200 + ch] = f2bf(v[p] - bf2f(hb));
        }
    }
    __syncthreads();
    const int wid = tid >> 6, lane = tid & 63;
    const int lr = lane & 15, lk = lane >> 4;
    const int mb = wid * 48;
    const ushort* Azh = Mh + (size_t)z * DIMC * DIMC;
    const ushort* Azl = Ml + (size_t)z * DIMC * DIMC;
    f32x4 acc[3][4];
#pragma unroll
    for (int i = 0; i < 3; i++)
#pragma unroll
        for (int j = 0; j < 4; j++) acc[i][j] = (f32x4)0.f;

    for (int kc6 = 0; kc6 < 6; kc6++) {
        short8 bh[4], bl[4];
#pragma unroll
        for (int j = 0; j < 4; j++) {
            int ad = (j * 16 + lr) * 200 + kc6 * 32 + lk * 8;
            bh[j] = *(const short8*)&BsH[ad];
            bl[j] = *(const short8*)&BsL[ad];
        }
#pragma unroll
        for (int i = 0; i < 3; i++) {
            size_t ao = (size_t)(mb + i * 16 + lr) * DIMC + kc6 * 32 + lk * 8;
            const short8 ah = *(const short8*)&Azh[ao];
            const short8 al = *(const short8*)&Azl[ao];
#pragma unroll
            for (int j = 0; j < 4; j++) {
                acc[i][j] = __builtin_amdgcn_mfma_f32_16x16x32_bf16(ah, bh[j], acc[i][j], 0, 0, 0);
                acc[i][j] = __builtin_amdgcn_mfma_f32_16x16x32_bf16(ah, bl[j], acc[i][j], 0, 0, 0);
                acc[i][j] = __builtin_amdgcn_mfma_f32_16x16x32_bf16(al, bh[j], acc[i][j], 0, 0, 0);
            }
        }
    }
    __syncthreads();  // all v reads done (LDS holds v); in-place writes + LDS reuse safe
    float* epsb = (float*)smem + wid * (2 * 1056);
#pragma unroll
    for (int i = 0; i < 3; i++) {
        float* eps = epsb + (i & 1) * 1056;
        int rb = mb + i * 16;
#pragma unroll
        for (int j = 0; j < 4; j++)
#pragma unroll
            for (int r = 0; r < 4; r++)
                eps[(lk * 4 + r) * 66 + j * 16 + lr] = acc[i][j][r] + bias[rb + lk * 4 + r];
#pragma unroll
        for (int s = 0; s < 4; s++) {
            int rl = s * 4 + (lane >> 4);
            int c4 = (lane & 15) * 4;
            f32x4 v = *(const f32x4*)&eps[rl * 66 + c4];
            *(f32x4*)&vb[(size_t)(rb + rl) * HWN + n0 + c4] = v;
        }
    }
}

// ============ K2: depthwise 3x3 + Gram/sumsq partials; v -> fp32 d_out ============
__global__ __launch_bounds__(1024, 4) void k2_dw(const float* __restrict__ qkv0, long qkv_zs,
                                                 const float* __restrict__ wdw,
                                                 const float* __restrict__ bdw,
                                                 float* __restrict__ vout,
                                                 float* __restrict__ part, int b0) {
    __shared__ float stage[2 * 6336];   // [2][8][6][132]
    __shared__ float qks[48 * 520];     // [qk ch][512 px + pad], fp32
    const int b = b0 + blockIdx.z;
    const float* qkv = qkv0 + (size_t)blockIdx.z * qkv_zs;
    const int stripe = blockIdx.x, h = blockIdx.y;
    const int tid = threadIdx.x;
    const int r0 = stripe * 4;

    const int col4 = (tid & 31) * 4;
    const int orow = (tid >> 5) & 3;
    const int cc = tid >> 7;  // 0..7

    auto stage_load = [&](int chunk, int buf) {
        const int g = chunk / 3, cb = (chunk % 3) * 8;
        float* sb = stage + buf * 6336;
#pragma unroll
        for (int f = tid; f < 1536; f += 1024) {
            int fc = f / 192, rem = f - fc * 192;
            int rl = rem >> 5, c4 = rem & 31;
            int gr = r0 - 1 + rl;
            int ch = g * DIMC + h * CDh + cb + fc;
            float4 v = make_float4(0.f, 0.f, 0.f, 0.f);
            if (gr >= 0 && gr < 128)
                v = *(const float4*)&qkv[(size_t)ch * HWN + gr * WIDTH + c4 * 4];
            *(float4*)&sb[(fc * 6 + rl) * 132 + c4 * 4] = v;
        }
    };

    stage_load(0, 0);
    __syncthreads();
    for (int chunk = 0; chunk < 9; chunk++) {
        const int buf = chunk & 1;
        if (chunk < 8) stage_load(chunk + 1, buf ^ 1);
        const int g = chunk / 3, cb = (chunk % 3) * 8;
        const float* sb = stage + buf * 6336;
        const int ch = g * DIMC + h * CDh + cb + cc;
        float wr[9];
#pragma unroll
        for (int t = 0; t < 9; t++) wr[t] = wdw[ch * 9 + t];
        float bsv = bdw[ch];
        float a0 = bsv, a1 = bsv, a2 = bsv, a3 = bsv;
#pragma unroll
        for (int dr = 0; dr < 3; dr++) {
            const float* row = &sb[(cc * 6 + orow + dr) * 132];
            f32x4 cen = *(const f32x4*)&row[col4];
            f32x4 lf4 = (col4 > 0) ? *(const f32x4*)&row[col4 - 4] : (f32x4)0.f;
            f32x4 rt4 = (col4 < 124) ? *(const f32x4*)&row[col4 + 4] : (f32x4)0.f;
            float left = lf4[3], right = rt4[0];
            float wA = wr[dr * 3 + 0], wB = wr[dr * 3 + 1], wC = wr[dr * 3 + 2];
            a0 = fmaf(left, wA, fmaf(cen[0], wB, fmaf(cen[1], wC, a0)));
            a1 = fmaf(cen[0], wA, fmaf(cen[1], wB, fmaf(cen[2], wC, a1)));
            a2 = fmaf(cen[1], wA, fmaf(cen[2], wB, fmaf(cen[3], wC, a2)));
            a3 = fmaf(cen[2], wA, fmaf(cen[3], wB, fmaf(right, wC, a3)));
        }
        if (g < 2) {
            float4 o4 = {a0, a1, a2, a3};
            *(float4*)&qks[(g * CDh + cb + cc) * 520 + orow * 128 + col4] = o4;
        } else {
            float4 o4 = {a0, a1, a2, a3};
            *(float4*)&vout[((size_t)b * DIMC + h * CDh + cb + cc) * HWN +
                            (size_t)(r0 + orow) * WIDTH + col4] = o4;
        }
        __syncthreads();
    }

    const int tc = tid & 3, td = (tid >> 2) & 3, tp = tid >> 4;
    float ga[6][6];
#pragma unroll
    for (int i = 0; i < 6; i++)
#pragma unroll
        for (int j = 0; j < 6; j++) ga[i][j] = 0.f;
#pragma unroll
    for (int s = 0; s < 2; s++) {
        int px = tp * 8 + s * 4;
        f32x4 qv[6], kv[6];
#pragma unroll
        for (int i = 0; i < 6; i++) qv[i] = *(const f32x4*)&qks[(tc * 6 + i) * 520 + px];
#pragma unroll
        for (int j = 0; j < 6; j++) kv[j] = *(const f32x4*)&qks[(24 + td * 6 + j) * 520 + px];
#pragma unroll
        for (int i = 0; i < 6; i++)
#pragma unroll
            for (int j = 0; j < 6; j++) {
                ga[i][j] = fmaf(qv[i][0], kv[j][0], ga[i][j]);
                ga[i][j] = fmaf(qv[i][1], kv[j][1], ga[i][j]);
                ga[i][j] = fmaf(qv[i][2], kv[j][2], ga[i][j]);
                ga[i][j] = fmaf(qv[i][3], kv[j][3], ga[i][j]);
            }
    }
#pragma unroll
    for (int i = 0; i < 6; i++)
#pragma unroll
        for (int j = 0; j < 6; j++) {
            float v = ga[i][j];
            v += __shfl_xor(v, 16, 64);
            v += __shfl_xor(v, 32, 64);
            ga[i][j] = v;
        }
    float nv = 0.f;
    int nch = 0, npg = 0;
    if (tid < 768) {
        npg = tid / 48;
        nch = tid - npg * 48;
#pragma unroll
        for (int s = 0; s < 8; s++) {
            f32x4 v = *(const f32x4*)&qks[nch * 520 + npg * 32 + s * 4];
            nv = fmaf(v[0], v[0], nv);
            nv = fmaf(v[1], v[1], nv);
            nv = fmaf(v[2], v[2], nv);
            nv = fmaf(v[3], v[3], nv);
        }
    }
    __syncthreads();
    float* gscr = qks;  // [16][624]
    const int wave = tid >> 6;
    if ((tid & 63) < 16) {
#pragma unroll
        for (int i = 0; i < 6; i++)
#pragma unroll
            for (int j = 0; j < 6; j++)
                gscr[wave * 624 + (tc * 6 + i) * 24 + (td * 6 + j)] = ga[i][j];
    }
    if (tid < 768) gscr[npg * 624 + 576 + nch] = nv;
    __syncthreads();
    if (tid < 624) {
        float s = 0.f;
#pragma unroll
        for (int w2 = 0; w2 < 16; w2++) s += gscr[w2 * 624 + tid];
        part[((size_t)(b * NHEADS + h) * 64 + stripe) * 624 + tid] = s;  // coalesced
    }
}

// ============ K34: reduce partials + attn + 4 top-k softmaxes -> A_eff ============
__global__ void k34_attn(const float* __restrict__ part, const float* __restrict__ temp,
                         const float* __restrict__ a1, const float* __restrict__ a2,
                         const float* __restrict__ a3, const float* __restrict__ a4,
                         float* __restrict__ Aeff) {
    __shared__ float gbuf[624];
    int bh = blockIdx.x;
    int h = bh & 7;
    int tid = threadIdx.x;
    for (int ti = tid; ti < 624; ti += 256) {
        float s = 0.f;
        const float* p = part + (size_t)bh * 64 * 624 + ti;
#pragma unroll 4
        for (int st = 0; st < 64; st++) s += p[st * 624];
        gbuf[ti] = s;
    }
    __syncthreads();
    int r = tid;
    if (r >= CDh) return;
    float t = temp[h];
    float aw[4] = {a1[0], a2[0], a3[0], a4[0]};
    const int kks[4] = {12, 16, 18, 19};
    float qn = fmaxf(sqrtf(gbuf[576 + r]), 1e-12f);
    float av[24];
    for (int d = 0; d < 24; d++) {
        float kn = fmaxf(sqrtf(gbuf[600 + d]), 1e-12f);
        av[d] = gbuf[r * 24 + d] / (qn * kn) * t;
    }
    int rank[24];
    float m = -1e30f;
    for (int d = 0; d < 24; d++) {
        int rk = 0;
        for (int e = 0; e < 24; e++)
            rk += (av[e] > av[d]) || (av[e] == av[d] && e < d);
        rank[d] = rk;
        m = fmaxf(m, av[d]);
    }
    float ex[24], outv[24];
    for (int d = 0; d < 24; d++) { ex[d] = expf(av[d] - m); outv[d] = 0.f; }
    for (int i = 0; i < 4; i++) {
        float Z = 0.f;
        for (int d = 0; d < 24; d++) if (rank[d] < kks[i]) Z += ex[d];
        float inv = aw[i] / Z;
        for (int d = 0; d < 24; d++) if (rank[d] < kks[i]) outv[d] += ex[d] * inv;
    }
    for (int d = 0; d < 24; d++) Aeff[(bh * 24 + r) * 24 + d] = outv[d];
}

// ============ K4b: M_b = W_proj @ blockdiag(A_eff) -> bf16 hi/lo ============
__global__ void k4b_mmat(const float* __restrict__ Wp, const float* __restrict__ Aeff,
                         ushort* __restrict__ Mh, ushort* __restrict__ Ml) {
    int b = blockIdx.x;
    int e0 = blockIdx.y * 6144;
    for (int e = e0 + threadIdx.x; e < e0 + 6144; e += 256) {
        int o = e / DIMC, j = e % DIMC;
        int h = j / CDh, d = j % CDh;
        const float* wrow = Wp + o * DIMC + h * CDh;
        const float* acol = Aeff + (size_t)((b * NHEADS + h) * CDh) * CDh + d;
        float s = 0.f;
        for (int c = 0; c < CDh; c++) s = fmaf(wrow[c], acol[c * CDh], s);
        size_t idx = ((size_t)b * DIMC + o) * DIMC + j;
        ushort hb = f2bf(s);
        Mh[idx] = hb;
        Ml[idx] = f2bf(s - bf2f(hb));
    }
}

extern "C" void kernel_launch(void* const* d_in, const int* in_sizes, int n_in,
                              void* d_out, int out_size, void* d_ws, size_t ws_size,
                              hipStream_t stream) {
    const float* x     = (const float*)d_in[0];
    const float* wqkv  = (const float*)d_in[1];
    const float* bqkv  = (const float*)d_in[2];
    const float* wdw   = (const float*)d_in[3];
    const float* bdw   = (const float*)d_in[4];
    const float* wproj = (const float*)d_in[5];
    const float* bproj = (const float*)d_in[6];
    const float* temp  = (const float*)d_in[7];
    const float* a1    = (const float*)d_in[8];
    const float* a2    = (const float*)d_in[9];
    const float* a3    = (const float*)d_in[10];
    const float* a4    = (const float*)d_in[11];
    float* out = (float*)d_out;

    float* ws = (float*)d_ws;
    const size_t fl_part = (size_t)64 * 64 * 624;
    const size_t fl_A    = (size_t)64 * 576;
    const size_t fl_M    = (size_t)NBATCH * DIMC * DIMC / 2;
    const size_t fl_W    = (size_t)C3 * DIMC / 2;
    const size_t fl_qkv1 = (size_t)C3 * HWN;
    const size_t base_fl = fl_part + fl_A + 2 * fl_M + 2 * fl_W;

    auto need = [&](int nzz) -> size_t {
        return (base_fl + (size_t)nzz * fl_qkv1) * sizeof(float);
    };
    int nz = 1;
    if (ws_size >= need(8))      nz = 8;
    else if (ws_size >= need(4)) nz = 4;
    else if (ws_size >= need(2)) nz = 2;

    size_t o = 0;
    float* part = ws + o; o += fl_part;
    float* Aeff = ws + o; o += fl_A;
    ushort* Mh  = (ushort*)(ws + o); o += fl_M;
    ushort* Ml  = (ushort*)(ws + o); o += fl_M;
    ushort* Wh  = (ushort*)(ws + o); o += fl_W;
    ushort* Wl  = (ushort*)(ws + o); o += fl_W;
    float* qkv  = ws + o;

    const long qkv_zs = (long)fl_qkv1;

    k0_prep<<<(C3 * DIMC + 255) / 256, 256, 0, stream>>>(wqkv, Wh, Wl, C3 * DIMC);

    for (int b0 = 0; b0 < NBATCH; b0 += nz) {
        kgx9<<<dim3(256, 1, nz), 256, 0, stream>>>(x + (size_t)b0 * DIMC * HWN,
                                                   Wh, Wl, bqkv, qkv, qkv_zs);
        k2_dw<<<dim3(32, 8, nz), 1024, 0, stream>>>(qkv, qkv_zs, wdw, bdw, out, part, b0);
    }
    k34_attn<<<64, 256, 0, stream>>>(part, temp, a1, a2, a3, a4, Aeff);
    k4b_mmat<<<dim3(8, 6), 256, 0, stream>>>(wproj, Aeff, Mh, Ml);
    kg3f<<<dim3(256, 8), 256, 0, stream>>>(out, Mh, Ml, bproj);
}

// Round 12
// 512.873 us; speedup vs baseline: 1.2666x; 1.2649x over previous
//
#include <hip/hip_runtime.h>
#include <math.h>

#define DIMC 192
#define C3 576
#define NHEADS 8
#define CDh 24
#define HWN 16384
#define WIDTH 128
#define NBATCH 8

typedef __attribute__((ext_vector_type(8))) short short8;
typedef __attribute__((ext_vector_type(4))) float f32x4;

__device__ __forceinline__ ushort f2bf(float f) {
    uint u = __float_as_uint(f);
    u += 0x7fff + ((u >> 16) & 1);
    return (ushort)(u >> 16);
}
__device__ __forceinline__ float bf2f(ushort h) {
    return __uint_as_float(((uint)h) << 16);
}

// ============ K0: split W_qkv -> bf16 hi/lo ============
__global__ void k0_prep(const float* __restrict__ W, ushort* __restrict__ Wh,
                        ushort* __restrict__ Wl, int n) {
    int i = blockIdx.x * 256 + threadIdx.x;
    if (i < n) {
        float w = W[i];
        ushort h = f2bf(w);
        Wh[i] = h;
        Wl[i] = f2bf(w - bf2f(h));
    }
}

// ============ KGX9: qkv = W @ x + b via split-bf16 MFMA; x fp32 staged+split in LDS ============
// grid (256 n-tiles of 64 px, 1, NZ), block 256 (4 waves; wave = 144 rows x 64 px).
// NOTE: launch_bounds min-waves MUST be 2: acc[9][4] needs 144 regs; (256,3) spills to
// scratch (R10/R11: VGPR=84, +1.3 GB scratch traffic, 3.5x slower).
__global__ __launch_bounds__(256, 2) void kgx9(const float* __restrict__ x,
                                               const ushort* __restrict__ Wh,
                                               const ushort* __restrict__ Wl,
                                               const float* __restrict__ bias,
                                               float* __restrict__ qkv, long qkv_zs) {
    __shared__ ushort smem[2 * 64 * 200];  // B-stage hi/lo; reused as f32 epilogue buf
    ushort* BsH = smem;
    ushort* BsL = smem + 64 * 200;
    const int z = blockIdx.z;
    const float* xb = x + (size_t)z * DIMC * HWN;
    const int n0 = blockIdx.x * 64;
    const int tid = threadIdx.x;
#pragma unroll
    for (int it = 0; it < 12; it++) {
        int idx = tid + it * 256;
        int ch = idx >> 4, q = idx & 15;
        f32x4 v = *(const f32x4*)&xb[(size_t)ch * HWN + n0 + q * 4];
#pragma unroll
        for (int p = 0; p < 4; p++) {
            ushort hb = f2bf(v[p]);
            BsH[(q * 4 + p) * 200 + ch] = hb;
            BsL[(q * 4 + p) * 200 + ch] = f2bf(v[p] - bf2f(hb));
        }
    }
    __syncthreads();
    const int wid = tid >> 6, lane = tid & 63;
    const int lr = lane & 15, lk = lane >> 4;
    const int mb = wid * 144;
    float* oz = qkv + (size_t)z * qkv_zs;
    f32x4 acc[9][4];
#pragma unroll
    for (int i = 0; i < 9; i++)
#pragma unroll
        for (int j = 0; j < 4; j++) acc[i][j] = (f32x4)0.f;

    for (int kc6 = 0; kc6 < 6; kc6++) {
        short8 bh[4], bl[4];
#pragma unroll
        for (int j = 0; j < 4; j++) {
            int ad = (j * 16 + lr) * 200 + kc6 * 32 + lk * 8;
            bh[j] = *(const short8*)&BsH[ad];
            bl[j] = *(const short8*)&BsL[ad];
        }
#pragma unroll
        for (int i = 0; i < 9; i++) {
            size_t ao = (size_t)(mb + i * 16 + lr) * DIMC + kc6 * 32 + lk * 8;
            const short8 ah = *(const short8*)&Wh[ao];
            const short8 al = *(const short8*)&Wl[ao];
#pragma unroll
            for (int j = 0; j < 4; j++) {
                acc[i][j] = __builtin_amdgcn_mfma_f32_16x16x32_bf16(ah, bh[j], acc[i][j], 0, 0, 0);
                acc[i][j] = __builtin_amdgcn_mfma_f32_16x16x32_bf16(ah, bl[j], acc[i][j], 0, 0, 0);
                acc[i][j] = __builtin_amdgcn_mfma_f32_16x16x32_bf16(al, bh[j], acc[i][j], 0, 0, 0);
            }
        }
    }
    __syncthreads();  // all waves done reading BsH/BsL -> reuse as epilogue staging
    float* epsb = (float*)smem + wid * (2 * 1056);  // per-wave double buffer [2][16][66]
#pragma unroll
    for (int i = 0; i < 9; i++) {
        float* eps = epsb + (i & 1) * 1056;
        int rb = mb + i * 16;
#pragma unroll
        for (int j = 0; j < 4; j++)
#pragma unroll
            for (int r = 0; r < 4; r++)
                eps[(lk * 4 + r) * 66 + j * 16 + lr] = acc[i][j][r] + bias[rb + lk * 4 + r];
#pragma unroll
        for (int s = 0; s < 4; s++) {
            int rl = s * 4 + (lane >> 4);
            int c4 = (lane & 15) * 4;
            f32x4 v = *(const f32x4*)&eps[rl * 66 + c4];
            *(f32x4*)&oz[(size_t)(rb + rl) * HWN + n0 + c4] = v;
        }
    }
}

// ============ KG3F: y = M_b @ v + b_proj, IN-PLACE on d_out; v fp32 staged+split in LDS ============
// grid (256 n-tiles of 64, 8 b), block 256 (4 waves; wave = 48 rows x 64 px).
__global__ __launch_bounds__(256, 3) void kg3f(float* __restrict__ vy,
                                               const ushort* __restrict__ Mh,
                                               const ushort* __restrict__ Ml,
                                               const float* __restrict__ bias) {
    __shared__ ushort smem[2 * 64 * 200];
    ushort* BsH = smem;
    ushort* BsL = smem + 64 * 200;
    const int z = blockIdx.y;
    float* vb = vy + (size_t)z * DIMC * HWN;
    const int n0 = blockIdx.x * 64;
    const int tid = threadIdx.x;
#pragma unroll
    for (int it = 0; it < 12; it++) {
        int idx = tid + it * 256;
        int ch = idx >> 4, q = idx & 15;
        f32x4 v = *(const f32x4*)&vb[(size_t)ch * HWN + n0 + q * 4];
#pragma unroll
        for (int p = 0; p < 4; p++) {
            ushort hb = f2bf(v[p]);
            BsH[(q * 4 + p) * 200 + ch] = hb;
            BsL[(q * 4 + p) * 200 + ch] = f2bf(v[p] - bf2f(hb));
        }
    }
    __syncthreads();
    const int wid = tid >> 6, lane = tid & 63;
    const int lr = lane & 15, lk = lane >> 4;
    const int mb = wid * 48;
    const ushort* Azh = Mh + (size_t)z * DIMC * DIMC;
    const ushort* Azl = Ml + (size_t)z * DIMC * DIMC;
    f32x4 acc[3][4];
#pragma unroll
    for (int i = 0; i < 3; i++)
#pragma unroll
        for (int j = 0; j < 4; j++) acc[i][j] = (f32x4)0.f;

    for (int kc6 = 0; kc6 < 6; kc6++) {
        short8 bh[4], bl[4];
#pragma unroll
        for (int j = 0; j < 4; j++) {
            int ad = (j * 16 + lr) * 200 + kc6 * 32 + lk * 8;
            bh[j] = *(const short8*)&BsH[ad];
            bl[j] = *(const short8*)&BsL[ad];
        }
#pragma unroll
        for (int i = 0; i < 3; i++) {
            size_t ao = (size_t)(mb + i * 16 + lr) * DIMC + kc6 * 32 + lk * 8;
            const short8 ah = *(const short8*)&Azh[ao];
            const short8 al = *(const short8*)&Azl[ao];
#pragma unroll
            for (int j = 0; j < 4; j++) {
                acc[i][j] = __builtin_amdgcn_mfma_f32_16x16x32_bf16(ah, bh[j], acc[i][j], 0, 0, 0);
                acc[i][j] = __builtin_amdgcn_mfma_f32_16x16x32_bf16(ah, bl[j], acc[i][j], 0, 0, 0);
                acc[i][j] = __builtin_amdgcn_mfma_f32_16x16x32_bf16(al, bh[j], acc[i][j], 0, 0, 0);
            }
        }
    }
    __syncthreads();  // all v reads done (LDS holds v); in-place writes + LDS reuse safe
    float* epsb = (float*)smem + wid * (2 * 1056);
#pragma unroll
    for (int i = 0; i < 3; i++) {
        float* eps = epsb + (i & 1) * 1056;
        int rb = mb + i * 16;
#pragma unroll
        for (int j = 0; j < 4; j++)
#pragma unroll
            for (int r = 0; r < 4; r++)
                eps[(lk * 4 + r) * 66 + j * 16 + lr] = acc[i][j][r] + bias[rb + lk * 4 + r];
#pragma unroll
        for (int s = 0; s < 4; s++) {
            int rl = s * 4 + (lane >> 4);
            int c4 = (lane & 15) * 4;
            f32x4 v = *(const f32x4*)&eps[rl * 66 + c4];
            *(f32x4*)&vb[(size_t)(rb + rl) * HWN + n0 + c4] = v;
        }
    }
}

// ============ K2: depthwise 3x3 + Gram/sumsq partials; v -> fp32 d_out ============
__global__ __launch_bounds__(1024, 4) void k2_dw(const float* __restrict__ qkv0, long qkv_zs,
                                                 const float* __restrict__ wdw,
                                                 const float* __restrict__ bdw,
                                                 float* __restrict__ vout,
                                                 float* __restrict__ part, int b0) {
    __shared__ float stage[2 * 6336];   // [2][8][6][132]
    __shared__ float qks[48 * 520];     // [qk ch][512 px + pad], fp32
    const int b = b0 + blockIdx.z;
    const float* qkv = qkv0 + (size_t)blockIdx.z * qkv_zs;
    const int stripe = blockIdx.x, h = blockIdx.y;
    const int tid = threadIdx.x;
    const int r0 = stripe * 4;

    const int col4 = (tid & 31) * 4;
    const int orow = (tid >> 5) & 3;
    const int cc = tid >> 7;  // 0..7

    auto stage_load = [&](int chunk, int buf) {
        const int g = chunk / 3, cb = (chunk % 3) * 8;
        float* sb = stage + buf * 6336;
#pragma unroll
        for (int f = tid; f < 1536; f += 1024) {
            int fc = f / 192, rem = f - fc * 192;
            int rl = rem >> 5, c4 = rem & 31;
            int gr = r0 - 1 + rl;
            int ch = g * DIMC + h * CDh + cb + fc;
            float4 v = make_float4(0.f, 0.f, 0.f, 0.f);
            if (gr >= 0 && gr < 128)
                v = *(const float4*)&qkv[(size_t)ch * HWN + gr * WIDTH + c4 * 4];
            *(float4*)&sb[(fc * 6 + rl) * 132 + c4 * 4] = v;
        }
    };

    stage_load(0, 0);
    __syncthreads();
    for (int chunk = 0; chunk < 9; chunk++) {
        const int buf = chunk & 1;
        if (chunk < 8) stage_load(chunk + 1, buf ^ 1);
        const int g = chunk / 3, cb = (chunk % 3) * 8;
        const float* sb = stage + buf * 6336;
        const int ch = g * DIMC + h * CDh + cb + cc;
        float wr[9];
#pragma unroll
        for (int t = 0; t < 9; t++) wr[t] = wdw[ch * 9 + t];
        float bsv = bdw[ch];
        float a0 = bsv, a1 = bsv, a2 = bsv, a3 = bsv;
#pragma unroll
        for (int dr = 0; dr < 3; dr++) {
            const float* row = &sb[(cc * 6 + orow + dr) * 132];
            f32x4 cen = *(const f32x4*)&row[col4];
            f32x4 lf4 = (col4 > 0) ? *(const f32x4*)&row[col4 - 4] : (f32x4)0.f;
            f32x4 rt4 = (col4 < 124) ? *(const f32x4*)&row[col4 + 4] : (f32x4)0.f;
            float left = lf4[3], right = rt4[0];
            float wA = wr[dr * 3 + 0], wB = wr[dr * 3 + 1], wC = wr[dr * 3 + 2];
            a0 = fmaf(left, wA, fmaf(cen[0], wB, fmaf(cen[1], wC, a0)));
            a1 = fmaf(cen[0], wA, fmaf(cen[1], wB, fmaf(cen[2], wC, a1)));
            a2 = fmaf(cen[1], wA, fmaf(cen[2], wB, fmaf(cen[3], wC, a2)));
            a3 = fmaf(cen[2], wA, fmaf(cen[3], wB, fmaf(right, wC, a3)));
        }
        if (g < 2) {
            float4 o4 = {a0, a1, a2, a3};
            *(float4*)&qks[(g * CDh + cb + cc) * 520 + orow * 128 + col4] = o4;
        } else {
            float4 o4 = {a0, a1, a2, a3};
            *(float4*)&vout[((size_t)b * DIMC + h * CDh + cb + cc) * HWN +
                            (size_t)(r0 + orow) * WIDTH + col4] = o4;
        }
        __syncthreads();
    }

    const int tc = tid & 3, td = (tid >> 2) & 3, tp = tid >> 4;
    float ga[6][6];
#pragma unroll
    for (int i = 0; i < 6; i++)
#pragma unroll
        for (int j = 0; j < 6; j++) ga[i][j] = 0.f;
#pragma unroll
    for (int s = 0; s < 2; s++) {
        int px = tp * 8 + s * 4;
        f32x4 qv[6], kv[6];
#pragma unroll
        for (int i = 0; i < 6; i++) qv[i] = *(const f32x4*)&qks[(tc * 6 + i) * 520 + px];
#pragma unroll
        for (int j = 0; j < 6; j++) kv[j] = *(const f32x4*)&qks[(24 + td * 6 + j) * 520 + px];
#pragma unroll
        for (int i = 0; i < 6; i++)
#pragma unroll
            for (int j = 0; j < 6; j++) {
                ga[i][j] = fmaf(qv[i][0], kv[j][0], ga[i][j]);
                ga[i][j] = fmaf(qv[i][1], kv[j][1], ga[i][j]);
                ga[i][j] = fmaf(qv[i][2], kv[j][2], ga[i][j]);
                ga[i][j] = fmaf(qv[i][3], kv[j][3], ga[i][j]);
            }
    }
#pragma unroll
    for (int i = 0; i < 6; i++)
#pragma unroll
        for (int j = 0; j < 6; j++) {
            float v = ga[i][j];
            v += __shfl_xor(v, 16, 64);
            v += __shfl_xor(v, 32, 64);
            ga[i][j] = v;
        }
    float nv = 0.f;
    int nch = 0, npg = 0;
    if (tid < 768) {
        npg = tid / 48;
        nch = tid - npg * 48;
#pragma unroll
        for (int s = 0; s < 8; s++) {
            f32x4 v = *(const f32x4*)&qks[nch * 520 + npg * 32 + s * 4];
            nv = fmaf(v[0], v[0], nv);
            nv = fmaf(v[1], v[1], nv);
            nv = fmaf(v[2], v[2], nv);
            nv = fmaf(v[3], v[3], nv);
        }
    }
    __syncthreads();
    float* gscr = qks;  // [16][624]
    const int wave = tid >> 6;
    if ((tid & 63) < 16) {
#pragma unroll
        for (int i = 0; i < 6; i++)
#pragma unroll
            for (int j = 0; j < 6; j++)
                gscr[wave * 624 + (tc * 6 + i) * 24 + (td * 6 + j)] = ga[i][j];
    }
    if (tid < 768) gscr[npg * 624 + 576 + nch] = nv;
    __syncthreads();
    if (tid < 624) {
        float s = 0.f;
#pragma unroll
        for (int w2 = 0; w2 < 16; w2++) s += gscr[w2 * 624 + tid];
        part[((size_t)(b * NHEADS + h) * 64 + stripe) * 624 + tid] = s;  // coalesced
    }
}

// ============ K34: reduce partials + attn + 4 top-k softmaxes -> A_eff ============
__global__ void k34_attn(const float* __restrict__ part, const float* __restrict__ temp,
                         const float* __restrict__ a1, const float* __restrict__ a2,
                         const float* __restrict__ a3, const float* __restrict__ a4,
                         float* __restrict__ Aeff) {
    __shared__ float gbuf[624];
    int bh = blockIdx.x;
    int h = bh & 7;
    int tid = threadIdx.x;
    for (int ti = tid; ti < 624; ti += 256) {
        float s = 0.f;
        const float* p = part + (size_t)bh * 64 * 624 + ti;
#pragma unroll 4
        for (int st = 0; st < 64; st++) s += p[st * 624];
        gbuf[ti] = s;
    }
    __syncthreads();
    int r = tid;
    if (r >= CDh) return;
    float t = temp[h];
    float aw[4] = {a1[0], a2[0], a3[0], a4[0]};
    const int kks[4] = {12, 16, 18, 19};
    float qn = fmaxf(sqrtf(gbuf[576 + r]), 1e-12f);
    float av[24];
    for (int d = 0; d < 24; d++) {
        float kn = fmaxf(sqrtf(gbuf[600 + d]), 1e-12f);
        av[d] = gbuf[r * 24 + d] / (qn * kn) * t;
    }
    int rank[24];
    float m = -1e30f;
    for (int d = 0; d < 24; d++) {
        int rk = 0;
        for (int e = 0; e < 24; e++)
            rk += (av[e] > av[d]) || (av[e] == av[d] && e < d);
        rank[d] = rk;
        m = fmaxf(m, av[d]);
    }
    float ex[24], outv[24];
    for (int d = 0; d < 24; d++) { ex[d] = expf(av[d] - m); outv[d] = 0.f; }
    for (int i = 0; i < 4; i++) {
        float Z = 0.f;
        for (int d = 0; d < 24; d++) if (rank[d] < kks[i]) Z += ex[d];
        float inv = aw[i] / Z;
        for (int d = 0; d < 24; d++) if (rank[d] < kks[i]) outv[d] += ex[d] * inv;
    }
    for (int d = 0; d < 24; d++) Aeff[(bh * 24 + r) * 24 + d] = outv[d];
}

// ============ K4b: M_b = W_proj @ blockdiag(A_eff) -> bf16 hi/lo ============
__global__ void k4b_mmat(const float* __restrict__ Wp, const float* __restrict__ Aeff,
                         ushort* __restrict__ Mh, ushort* __restrict__ Ml) {
    int b = blockIdx.x;
    int e0 = blockIdx.y * 6144;
    for (int e = e0 + threadIdx.x; e < e0 + 6144; e += 256) {
        int o = e / DIMC, j = e % DIMC;
        int h = j / CDh, d = j % CDh;
        const float* wrow = Wp + o * DIMC + h * CDh;
        const float* acol = Aeff + (size_t)((b * NHEADS + h) * CDh) * CDh + d;
        float s = 0.f;
        for (int c = 0; c < CDh; c++) s = fmaf(wrow[c], acol[c * CDh], s);
        size_t idx = ((size_t)b * DIMC + o) * DIMC + j;
        ushort hb = f2bf(s);
        Mh[idx] = hb;
        Ml[idx] = f2bf(s - bf2f(hb));
    }
}

extern "C" void kernel_launch(void* const* d_in, const int* in_sizes, int n_in,
                              void* d_out, int out_size, void* d_ws, size_t ws_size,
                              hipStream_t stream) {
    const float* x     = (const float*)d_in[0];
    const float* wqkv  = (const float*)d_in[1];
    const float* bqkv  = (const float*)d_in[2];
    const float* wdw   = (const float*)d_in[3];
    const float* bdw   = (const float*)d_in[4];
    const float* wproj = (const float*)d_in[5];
    const float* bproj = (const float*)d_in[6];
    const float* temp  = (const float*)d_in[7];
    const float* a1    = (const float*)d_in[8];
    const float* a2    = (const float*)d_in[9];
    const float* a3    = (const float*)d_in[10];
    const float* a4    = (const float*)d_in[11];
    float* out = (float*)d_out;

    float* ws = (float*)d_ws;
    const size_t fl_part = (size_t)64 * 64 * 624;
    const size_t fl_A    = (size_t)64 * 576;
    const size_t fl_M    = (size_t)NBATCH * DIMC * DIMC / 2;
    const size_t fl_W    = (size_t)C3 * DIMC / 2;
    const size_t fl_qkv1 = (size_t)C3 * HWN;
    const size_t base_fl = fl_part + fl_A + 2 * fl_M + 2 * fl_W;

    auto need = [&](int nzz) -> size_t {
        return (base_fl + (size_t)nzz * fl_qkv1) * sizeof(float);
    };
    int nz = 1;
    if (ws_size >= need(8))      nz = 8;
    else if (ws_size >= need(4)) nz = 4;
    else if (ws_size >= need(2)) nz = 2;

    size_t o = 0;
    float* part = ws + o; o += fl_part;
    float* Aeff = ws + o; o += fl_A;
    ushort* Mh  = (ushort*)(ws + o); o += fl_M;
    ushort* Ml  = (ushort*)(ws + o); o += fl_M;
    ushort* Wh  = (ushort*)(ws + o); o += fl_W;
    ushort* Wl  = (ushort*)(ws + o); o += fl_W;
    float* qkv  = ws + o;

    const long qkv_zs = (long)fl_qkv1;

    k0_prep<<<(C3 * DIMC + 255) / 256, 256, 0, stream>>>(wqkv, Wh, Wl, C3 * DIMC);

    for (int b0 = 0; b0 < NBATCH; b0 += nz) {
        kgx9<<<dim3(256, 1, nz), 256, 0, stream>>>(x + (size_t)b0 * DIMC * HWN,
                                                   Wh, Wl, bqkv, qkv, qkv_zs);
        k2_dw<<<dim3(32, 8, nz), 1024, 0, stream>>>(qkv, qkv_zs, wdw, bdw, out, part, b0);
    }
    k34_attn<<<64, 256, 0, stream>>>(part, temp, a1, a2, a3, a4, Aeff);
    k4b_mmat<<<dim3(8, 6), 256, 0, stream>>>(wproj, Aeff, Mh, Ml);
    kg3f<<<dim3(256, 8), 256, 0, stream>>>(out, Mh, Ml, bproj);
}

// Round 13
// 493.703 us; speedup vs baseline: 1.3158x; 1.0388x over previous
//
#include <hip/hip_runtime.h>
#include <math.h>

#define DIMC 192
#define C3 576
#define NHEADS 8
#define CDh 24
#define HWN 16384
#define WIDTH 128
#define NBATCH 8

typedef __attribute__((ext_vector_type(8))) short short8;
typedef __attribute__((ext_vector_type(4))) float f32x4;

__device__ __forceinline__ ushort f2bf(float f) {
    uint u = __float_as_uint(f);
    u += 0x7fff + ((u >> 16) & 1);
    return (ushort)(u >> 16);
}
__device__ __forceinline__ float bf2f(ushort h) {
    return __uint_as_float(((uint)h) << 16);
}

// ============ K0: split W_qkv -> bf16 hi/lo ============
__global__ void k0_prep(const float* __restrict__ W, ushort* __restrict__ Wh,
                        ushort* __restrict__ Wl, int n) {
    int i = blockIdx.x * 256 + threadIdx.x;
    if (i < n) {
        float w = W[i];
        ushort h = f2bf(w);
        Wh[i] = h;
        Wl[i] = f2bf(w - bf2f(h));
    }
}

// ============ KGX3: qkv = W @ x + b via split-bf16 MFMA; x fp32 staged+split in LDS ============
// grid (256 n-tiles of 64 px, 3 m-tiles of 192, 1 batch), block 256 (4 waves; wave=48r x 64px).
// NI=3 m-split -> 768 blocks/batch (3/CU) for latency hiding at nz=1 (L3-blocked schedule).
__global__ __launch_bounds__(256, 3) void kgx3(const float* __restrict__ x,
                                               const ushort* __restrict__ Wh,
                                               const ushort* __restrict__ Wl,
                                               const float* __restrict__ bias,
                                               float* __restrict__ qkv) {
    __shared__ ushort smem[2 * 64 * 200];  // B-stage hi/lo; reused as f32 epilogue buf
    ushort* BsH = smem;
    ushort* BsL = smem + 64 * 200;
    const int n0 = blockIdx.x * 64;
    const int o0 = blockIdx.y * 192;
    const int tid = threadIdx.x;
#pragma unroll
    for (int it = 0; it < 12; it++) {
        int idx = tid + it * 256;
        int ch = idx >> 4, q = idx & 15;
        f32x4 v = *(const f32x4*)&x[(size_t)ch * HWN + n0 + q * 4];
#pragma unroll
        for (int p = 0; p < 4; p++) {
            ushort hb = f2bf(v[p]);
            BsH[(q * 4 + p) * 200 + ch] = hb;
            BsL[(q * 4 + p) * 200 + ch] = f2bf(v[p] - bf2f(hb));
        }
    }
    __syncthreads();
    const int wid = tid >> 6, lane = tid & 63;
    const int lr = lane & 15, lk = lane >> 4;
    const int mb = o0 + wid * 48;
    f32x4 acc[3][4];
#pragma unroll
    for (int i = 0; i < 3; i++)
#pragma unroll
        for (int j = 0; j < 4; j++) acc[i][j] = (f32x4)0.f;

    for (int kc6 = 0; kc6 < 6; kc6++) {
        short8 bh[4], bl[4];
#pragma unroll
        for (int j = 0; j < 4; j++) {
            int ad = (j * 16 + lr) * 200 + kc6 * 32 + lk * 8;
            bh[j] = *(const short8*)&BsH[ad];
            bl[j] = *(const short8*)&BsL[ad];
        }
#pragma unroll
        for (int i = 0; i < 3; i++) {
            size_t ao = (size_t)(mb + i * 16 + lr) * DIMC + kc6 * 32 + lk * 8;
            const short8 ah = *(const short8*)&Wh[ao];
            const short8 al = *(const short8*)&Wl[ao];
#pragma unroll
            for (int j = 0; j < 4; j++) {
                acc[i][j] = __builtin_amdgcn_mfma_f32_16x16x32_bf16(ah, bh[j], acc[i][j], 0, 0, 0);
                acc[i][j] = __builtin_amdgcn_mfma_f32_16x16x32_bf16(ah, bl[j], acc[i][j], 0, 0, 0);
                acc[i][j] = __builtin_amdgcn_mfma_f32_16x16x32_bf16(al, bh[j], acc[i][j], 0, 0, 0);
            }
        }
    }
    __syncthreads();  // all waves done reading BsH/BsL -> reuse as epilogue staging
    float* epsb = (float*)smem + wid * (2 * 1056);  // per-wave double buffer [2][16][66]
#pragma unroll
    for (int i = 0; i < 3; i++) {
        float* eps = epsb + (i & 1) * 1056;
        int rb = mb + i * 16;
#pragma unroll
        for (int j = 0; j < 4; j++)
#pragma unroll
            for (int r = 0; r < 4; r++)
                eps[(lk * 4 + r) * 66 + j * 16 + lr] = acc[i][j][r] + bias[rb + lk * 4 + r];
#pragma unroll
        for (int s = 0; s < 4; s++) {
            int rl = s * 4 + (lane >> 4);
            int c4 = (lane & 15) * 4;
            f32x4 v = *(const f32x4*)&eps[rl * 66 + c4];
            *(f32x4*)&qkv[(size_t)(rb + rl) * HWN + n0 + c4] = v;
        }
    }
}

// ============ KG3F: y = M_b @ v + b_proj, IN-PLACE on d_out; v fp32 staged+split in LDS ============
// grid (256 n-tiles of 64, 8 b), block 256 (4 waves; wave = 48 rows x 64 px).
__global__ __launch_bounds__(256, 3) void kg3f(float* __restrict__ vy,
                                               const ushort* __restrict__ Mh,
                                               const ushort* __restrict__ Ml,
                                               const float* __restrict__ bias) {
    __shared__ ushort smem[2 * 64 * 200];
    ushort* BsH = smem;
    ushort* BsL = smem + 64 * 200;
    const int z = blockIdx.y;
    float* vb = vy + (size_t)z * DIMC * HWN;
    const int n0 = blockIdx.x * 64;
    const int tid = threadIdx.x;
#pragma unroll
    for (int it = 0; it < 12; it++) {
        int idx = tid + it * 256;
        int ch = idx >> 4, q = idx & 15;
        f32x4 v = *(const f32x4*)&vb[(size_t)ch * HWN + n0 + q * 4];
#pragma unroll
        for (int p = 0; p < 4; p++) {
            ushort hb = f2bf(v[p]);
            BsH[(q * 4 + p) * 200 + ch] = hb;
            BsL[(q * 4 + p) * 200 + ch] = f2bf(v[p] - bf2f(hb));
        }
    }
    __syncthreads();
    const int wid = tid >> 6, lane = tid & 63;
    const int lr = lane & 15, lk = lane >> 4;
    const int mb = wid * 48;
    const ushort* Azh = Mh + (size_t)z * DIMC * DIMC;
    const ushort* Azl = Ml + (size_t)z * DIMC * DIMC;
    f32x4 acc[3][4];
#pragma unroll
    for (int i = 0; i < 3; i++)
#pragma unroll
        for (int j = 0; j < 4; j++) acc[i][j] = (f32x4)0.f;

    for (int kc6 = 0; kc6 < 6; kc6++) {
        short8 bh[4], bl[4];
#pragma unroll
        for (int j = 0; j < 4; j++) {
            int ad = (j * 16 + lr) * 200 + kc6 * 32 + lk * 8;
            bh[j] = *(const short8*)&BsH[ad];
            bl[j] = *(const short8*)&BsL[ad];
        }
#pragma unroll
        for (int i = 0; i < 3; i++) {
            size_t ao = (size_t)(mb + i * 16 + lr) * DIMC + kc6 * 32 + lk * 8;
            const short8 ah = *(const short8*)&Azh[ao];
            const short8 al = *(const short8*)&Azl[ao];
#pragma unroll
            for (int j = 0; j < 4; j++) {
                acc[i][j] = __builtin_amdgcn_mfma_f32_16x16x32_bf16(ah, bh[j], acc[i][j], 0, 0, 0);
                acc[i][j] = __builtin_amdgcn_mfma_f32_16x16x32_bf16(ah, bl[j], acc[i][j], 0, 0, 0);
                acc[i][j] = __builtin_amdgcn_mfma_f32_16x16x32_bf16(al, bh[j], acc[i][j], 0, 0, 0);
            }
        }
    }
    __syncthreads();  // all v reads done (LDS holds v); in-place writes + LDS reuse safe
    float* epsb = (float*)smem + wid * (2 * 1056);
#pragma unroll
    for (int i = 0; i < 3; i++) {
        float* eps = epsb + (i & 1) * 1056;
        int rb = mb + i * 16;
#pragma unroll
        for (int j = 0; j < 4; j++)
#pragma unroll
            for (int r = 0; r < 4; r++)
                eps[(lk * 4 + r) * 66 + j * 16 + lr] = acc[i][j][r] + bias[rb + lk * 4 + r];
#pragma unroll
        for (int s = 0; s < 4; s++) {
            int rl = s * 4 + (lane >> 4);
            int c4 = (lane & 15) * 4;
            f32x4 v = *(const f32x4*)&eps[rl * 66 + c4];
            *(f32x4*)&vb[(size_t)(rb + rl) * HWN + n0 + c4] = v;
        }
    }
}

// ============ K2: depthwise 3x3 + Gram/sumsq partials; v -> fp32 d_out ============
// grid (32 stripes of 4 rows, 8 heads), block 1024 (16 waves), 1 batch per launch.
__global__ __launch_bounds__(1024, 4) void k2_dw(const float* __restrict__ qkv,
                                                 const float* __restrict__ wdw,
                                                 const float* __restrict__ bdw,
                                                 float* __restrict__ vout,
                                                 float* __restrict__ part, int b) {
    __shared__ float stage[2 * 6336];   // [2][8][6][132]
    __shared__ float qks[48 * 520];     // [qk ch][512 px + pad], fp32
    const int stripe = blockIdx.x, h = blockIdx.y;
    const int tid = threadIdx.x;
    const int r0 = stripe * 4;

    const int col4 = (tid & 31) * 4;
    const int orow = (tid >> 5) & 3;
    const int cc = tid >> 7;  // 0..7

    auto stage_load = [&](int chunk, int buf) {
        const int g = chunk / 3, cb = (chunk % 3) * 8;
        float* sb = stage + buf * 6336;
#pragma unroll
        for (int f = tid; f < 1536; f += 1024) {
            int fc = f / 192, rem = f - fc * 192;
            int rl = rem >> 5, c4 = rem & 31;
            int gr = r0 - 1 + rl;
            int ch = g * DIMC + h * CDh + cb + fc;
            float4 v = make_float4(0.f, 0.f, 0.f, 0.f);
            if (gr >= 0 && gr < 128)
                v = *(const float4*)&qkv[(size_t)ch * HWN + gr * WIDTH + c4 * 4];
            *(float4*)&sb[(fc * 6 + rl) * 132 + c4 * 4] = v;
        }
    };

    stage_load(0, 0);
    __syncthreads();
    for (int chunk = 0; chunk < 9; chunk++) {
        const int buf = chunk & 1;
        if (chunk < 8) stage_load(chunk + 1, buf ^ 1);
        const int g = chunk / 3, cb = (chunk % 3) * 8;
        const float* sb = stage + buf * 6336;
        const int ch = g * DIMC + h * CDh + cb + cc;
        float wr[9];
#pragma unroll
        for (int t = 0; t < 9; t++) wr[t] = wdw[ch * 9 + t];
        float bsv = bdw[ch];
        float a0 = bsv, a1 = bsv, a2 = bsv, a3 = bsv;
#pragma unroll
        for (int dr = 0; dr < 3; dr++) {
            const float* row = &sb[(cc * 6 + orow + dr) * 132];
            f32x4 cen = *(const f32x4*)&row[col4];
            f32x4 lf4 = (col4 > 0) ? *(const f32x4*)&row[col4 - 4] : (f32x4)0.f;
            f32x4 rt4 = (col4 < 124) ? *(const f32x4*)&row[col4 + 4] : (f32x4)0.f;
            float left = lf4[3], right = rt4[0];
            float wA = wr[dr * 3 + 0], wB = wr[dr * 3 + 1], wC = wr[dr * 3 + 2];
            a0 = fmaf(left, wA, fmaf(cen[0], wB, fmaf(cen[1], wC, a0)));
            a1 = fmaf(cen[0], wA, fmaf(cen[1], wB, fmaf(cen[2], wC, a1)));
            a2 = fmaf(cen[1], wA, fmaf(cen[2], wB, fmaf(cen[3], wC, a2)));
            a3 = fmaf(cen[2], wA, fmaf(cen[3], wB, fmaf(right, wC, a3)));
        }
        if (g < 2) {
            float4 o4 = {a0, a1, a2, a3};
            *(float4*)&qks[(g * CDh + cb + cc) * 520 + orow * 128 + col4] = o4;
        } else {
            float4 o4 = {a0, a1, a2, a3};
            *(float4*)&vout[((size_t)b * DIMC + h * CDh + cb + cc) * HWN +
                            (size_t)(r0 + orow) * WIDTH + col4] = o4;
        }
        __syncthreads();
    }

    const int tc = tid & 3, td = (tid >> 2) & 3, tp = tid >> 4;
    float ga[6][6];
#pragma unroll
    for (int i = 0; i < 6; i++)
#pragma unroll
        for (int j = 0; j < 6; j++) ga[i][j] = 0.f;
#pragma unroll
    for (int s = 0; s < 2; s++) {
        int px = tp * 8 + s * 4;
        f32x4 qv[6], kv[6];
#pragma unroll
        for (int i = 0; i < 6; i++) qv[i] = *(const f32x4*)&qks[(tc * 6 + i) * 520 + px];
#pragma unroll
        for (int j = 0; j < 6; j++) kv[j] = *(const f32x4*)&qks[(24 + td * 6 + j) * 520 + px];
#pragma unroll
        for (int i = 0; i < 6; i++)
#pragma unroll
            for (int j = 0; j < 6; j++) {
                ga[i][j] = fmaf(qv[i][0], kv[j][0], ga[i][j]);
                ga[i][j] = fmaf(qv[i][1], kv[j][1], ga[i][j]);
                ga[i][j] = fmaf(qv[i][2], kv[j][2], ga[i][j]);
                ga[i][j] = fmaf(qv[i][3], kv[j][3], ga[i][j]);
            }
    }
#pragma unroll
    for (int i = 0; i < 6; i++)
#pragma unroll
        for (int j = 0; j < 6; j++) {
            float v = ga[i][j];
            v += __shfl_xor(v, 16, 64);
            v += __shfl_xor(v, 32, 64);
            ga[i][j] = v;
        }
    float nv = 0.f;
    int nch = 0, npg = 0;
    if (tid < 768) {
        npg = tid / 48;
        nch = tid - npg * 48;
#pragma unroll
        for (int s = 0; s < 8; s++) {
            f32x4 v = *(const f32x4*)&qks[nch * 520 + npg * 32 + s * 4];
            nv = fmaf(v[0], v[0], nv);
            nv = fmaf(v[1], v[1], nv);
            nv = fmaf(v[2], v[2], nv);
            nv = fmaf(v[3], v[3], nv);
        }
    }
    __syncthreads();
    float* gscr = qks;  // [16][624]
    const int wave = tid >> 6;
    if ((tid & 63) < 16) {
#pragma unroll
        for (int i = 0; i < 6; i++)
#pragma unroll
            for (int j = 0; j < 6; j++)
                gscr[wave * 624 + (tc * 6 + i) * 24 + (td * 6 + j)] = ga[i][j];
    }
    if (tid < 768) gscr[npg * 624 + 576 + nch] = nv;
    __syncthreads();
    if (tid < 624) {
        float s = 0.f;
#pragma unroll
        for (int w2 = 0; w2 < 16; w2++) s += gscr[w2 * 624 + tid];
        part[((size_t)(b * NHEADS + h) * 64 + stripe) * 624 + tid] = s;  // coalesced
    }
}

// ============ K34: reduce partials + attn + 4 top-k softmaxes -> A_eff ============
__global__ void k34_attn(const float* __restrict__ part, const float* __restrict__ temp,
                         const float* __restrict__ a1, const float* __restrict__ a2,
                         const float* __restrict__ a3, const float* __restrict__ a4,
                         float* __restrict__ Aeff) {
    __shared__ float gbuf[624];
    int bh = blockIdx.x;
    int h = bh & 7;
    int tid = threadIdx.x;
    for (int ti = tid; ti < 624; ti += 256) {
        float s = 0.f;
        const float* p = part + (size_t)bh * 64 * 624 + ti;
#pragma unroll 4
        for (int st = 0; st < 64; st++) s += p[st * 624];
        gbuf[ti] = s;
    }
    __syncthreads();
    int r = tid;
    if (r >= CDh) return;
    float t = temp[h];
    float aw[4] = {a1[0], a2[0], a3[0], a4[0]};
    const int kks[4] = {12, 16, 18, 19};
    float qn = fmaxf(sqrtf(gbuf[576 + r]), 1e-12f);
    float av[24];
    for (int d = 0; d < 24; d++) {
        float kn = fmaxf(sqrtf(gbuf[600 + d]), 1e-12f);
        av[d] = gbuf[r * 24 + d] / (qn * kn) * t;
    }
    int rank[24];
    float m = -1e30f;
    for (int d = 0; d < 24; d++) {
        int rk = 0;
        for (int e = 0; e < 24; e++)
            rk += (av[e] > av[d]) || (av[e] == av[d] && e < d);
        rank[d] = rk;
        m = fmaxf(m, av[d]);
    }
    float ex[24], outv[24];
    for (int d = 0; d < 24; d++) { ex[d] = expf(av[d] - m); outv[d] = 0.f; }
    for (int i = 0; i < 4; i++) {
        float Z = 0.f;
        for (int d = 0; d < 24; d++) if (rank[d] < kks[i]) Z += ex[d];
        float inv = aw[i] / Z;
        for (int d = 0; d < 24; d++) if (rank[d] < kks[i]) outv[d] += ex[d] * inv;
    }
    for (int d = 0; d < 24; d++) Aeff[(bh * 24 + r) * 24 + d] = outv[d];
}

// ============ K4b: M_b = W_proj @ blockdiag(A_eff) -> bf16 hi/lo ============
__global__ void k4b_mmat(const float* __restrict__ Wp, const float* __restrict__ Aeff,
                         ushort* __restrict__ Mh, ushort* __restrict__ Ml) {
    int b = blockIdx.x;
    int e0 = blockIdx.y * 6144;
    for (int e = e0 + threadIdx.x; e < e0 + 6144; e += 256) {
        int o = e / DIMC, j = e % DIMC;
        int h = j / CDh, d = j % CDh;
        const float* wrow = Wp + o * DIMC + h * CDh;
        const float* acol = Aeff + (size_t)((b * NHEADS + h) * CDh) * CDh + d;
        float s = 0.f;
        for (int c = 0; c < CDh; c++) s = fmaf(wrow[c], acol[c * CDh], s);
        size_t idx = ((size_t)b * DIMC + o) * DIMC + j;
        ushort hb = f2bf(s);
        Mh[idx] = hb;
        Ml[idx] = f2bf(s - bf2f(hb));
    }
}

extern "C" void kernel_launch(void* const* d_in, const int* in_sizes, int n_in,
                              void* d_out, int out_size, void* d_ws, size_t ws_size,
                              hipStream_t stream) {
    const float* x     = (const float*)d_in[0];
    const float* wqkv  = (const float*)d_in[1];
    const float* bqkv  = (const float*)d_in[2];
    const float* wdw   = (const float*)d_in[3];
    const float* bdw   = (const float*)d_in[4];
    const float* wproj = (const float*)d_in[5];
    const float* bproj = (const float*)d_in[6];
    const float* temp  = (const float*)d_in[7];
    const float* a1    = (const float*)d_in[8];
    const float* a2    = (const float*)d_in[9];
    const float* a3    = (const float*)d_in[10];
    const float* a4    = (const float*)d_in[11];
    float* out = (float*)d_out;

    float* ws = (float*)d_ws;
    const size_t fl_part = (size_t)64 * 64 * 624;
    const size_t fl_A    = (size_t)64 * 576;
    const size_t fl_M    = (size_t)NBATCH * DIMC * DIMC / 2;
    const size_t fl_W    = (size_t)C3 * DIMC / 2;
    const size_t fl_qkv1 = (size_t)C3 * HWN;

    size_t o = 0;
    float* part = ws + o; o += fl_part;
    float* Aeff = ws + o; o += fl_A;
    ushort* Mh  = (ushort*)(ws + o); o += fl_M;
    ushort* Ml  = (ushort*)(ws + o); o += fl_M;
    ushort* Wh  = (ushort*)(ws + o); o += fl_W;
    ushort* Wl  = (ushort*)(ws + o); o += fl_W;
    float* qkv  = ws + o;  // single batch: 9.44M floats (~38 MB); total ws use ~50 MB
    (void)fl_qkv1;

    k0_prep<<<(C3 * DIMC + 255) / 256, 256, 0, stream>>>(wqkv, Wh, Wl, C3 * DIMC);

    // L3-blocked schedule: per batch, produce qkv (151 MB, L3-resident) then
    // immediately consume it in k2 — qkv never round-trips to HBM.
    for (int b = 0; b < NBATCH; b++) {
        kgx3<<<dim3(256, 3), 256, 0, stream>>>(x + (size_t)b * DIMC * HWN,
                                               Wh, Wl, bqkv, qkv);
        k2_dw<<<dim3(32, 8), 1024, 0, stream>>>(qkv, wdw, bdw, out, part, b);
    }
    k34_attn<<<64, 256, 0, stream>>>(part, temp, a1, a2, a3, a4, Aeff);
    k4b_mmat<<<dim3(8, 6), 256, 0, stream>>>(wproj, Aeff, Mh, Ml);
    kg3f<<<dim3(256, 8), 256, 0, stream>>>(out, Mh, Ml, bproj);
}

// Round 14
// 459.923 us; speedup vs baseline: 1.4124x; 1.0734x over previous
//
#include <hip/hip_runtime.h>
#include <math.h>

#define DIMC 192
#define C3 576
#define NHEADS 8
#define CDh 24
#define HWN 16384
#define WIDTH 128
#define NBATCH 8

typedef __attribute__((ext_vector_type(8))) short short8;
typedef __attribute__((ext_vector_type(4))) float f32x4;

__device__ __forceinline__ ushort f2bf(float f) {
    uint u = __float_as_uint(f);
    u += 0x7fff + ((u >> 16) & 1);
    return (ushort)(u >> 16);
}
__device__ __forceinline__ float bf2f(ushort h) {
    return __uint_as_float(((uint)h) << 16);
}

// ============ K0: split W_qkv -> bf16 hi/lo ============
__global__ void k0_prep(const float* __restrict__ W, ushort* __restrict__ Wh,
                        ushort* __restrict__ Wl, int n) {
    int i = blockIdx.x * 256 + threadIdx.x;
    if (i < n) {
        float w = W[i];
        ushort h = f2bf(w);
        Wh[i] = h;
        Wl[i] = f2bf(w - bf2f(h));
    }
}

// ============ KGX3: qkv = W @ x + b via split-bf16 MFMA; x fp32 staged+split in LDS ============
// grid (256 n-tiles of 64 px, 3 m-tiles of 192, NZ), block 256 (4 waves; wave=48r x 64px).
// LDS B-tile uses oct XOR-swizzle (oct ^= (px>>2)&7): staging stores spread 8 banks
// instead of 2 (was ~16-way conflict, 14.9M conflict-cycles/dispatch).
__global__ __launch_bounds__(256, 3) void kgx3(const float* __restrict__ x,
                                               const ushort* __restrict__ Wh,
                                               const ushort* __restrict__ Wl,
                                               const float* __restrict__ bias,
                                               float* __restrict__ qkv, long qkv_zs) {
    __shared__ ushort smem[2 * 64 * 200];  // B-stage hi/lo; reused as f32 epilogue buf
    ushort* BsH = smem;
    ushort* BsL = smem + 64 * 200;
    const float* xb = x + (size_t)blockIdx.z * DIMC * HWN;
    float* oz = qkv + (size_t)blockIdx.z * qkv_zs;
    const int n0 = blockIdx.x * 64;
    const int o0 = blockIdx.y * 192;
    const int tid = threadIdx.x;
#pragma unroll
    for (int it = 0; it < 12; it++) {
        int idx = tid + it * 256;
        int ch = idx >> 4, q = idx & 15;
        f32x4 v = *(const f32x4*)&xb[(size_t)ch * HWN + n0 + q * 4];
        const int swz = ((ch >> 3) ^ (q & 7)) * 8 + (ch & 7);
#pragma unroll
        for (int p = 0; p < 4; p++) {
            int ad = (q * 4 + p) * 200 + swz;
            ushort hb = f2bf(v[p]);
            BsH[ad] = hb;
            BsL[ad] = f2bf(v[p] - bf2f(hb));
        }
    }
    __syncthreads();
    const int wid = tid >> 6, lane = tid & 63;
    const int lr = lane & 15, lk = lane >> 4;
    const int mb = o0 + wid * 48;
    f32x4 acc[3][4];
#pragma unroll
    for (int i = 0; i < 3; i++)
#pragma unroll
        for (int j = 0; j < 4; j++) acc[i][j] = (f32x4)0.f;

    for (int kc6 = 0; kc6 < 6; kc6++) {
        short8 bh[4], bl[4];
#pragma unroll
        for (int j = 0; j < 4; j++) {
            int px = j * 16 + lr;
            int o = (kc6 * 4 + lk) ^ ((px >> 2) & 7);
            int ad = px * 200 + o * 8;
            bh[j] = *(const short8*)&BsH[ad];
            bl[j] = *(const short8*)&BsL[ad];
        }
#pragma unroll
        for (int i = 0; i < 3; i++) {
            size_t ao = (size_t)(mb + i * 16 + lr) * DIMC + kc6 * 32 + lk * 8;
            const short8 ah = *(const short8*)&Wh[ao];
            const short8 al = *(const short8*)&Wl[ao];
#pragma unroll
            for (int j = 0; j < 4; j++) {
                acc[i][j] = __builtin_amdgcn_mfma_f32_16x16x32_bf16(ah, bh[j], acc[i][j], 0, 0, 0);
                acc[i][j] = __builtin_amdgcn_mfma_f32_16x16x32_bf16(ah, bl[j], acc[i][j], 0, 0, 0);
                acc[i][j] = __builtin_amdgcn_mfma_f32_16x16x32_bf16(al, bh[j], acc[i][j], 0, 0, 0);
            }
        }
    }
    __syncthreads();  // all waves done reading BsH/BsL -> reuse as epilogue staging
    float* epsb = (float*)smem + wid * (2 * 1056);  // per-wave double buffer [2][16][66]
#pragma unroll
    for (int i = 0; i < 3; i++) {
        float* eps = epsb + (i & 1) * 1056;
        int rb = mb + i * 16;
#pragma unroll
        for (int j = 0; j < 4; j++)
#pragma unroll
            for (int r = 0; r < 4; r++)
                eps[(lk * 4 + r) * 66 + j * 16 + lr] = acc[i][j][r] + bias[rb + lk * 4 + r];
#pragma unroll
        for (int s = 0; s < 4; s++) {
            int rl = s * 4 + (lane >> 4);
            int c4 = (lane & 15) * 4;
            f32x4 v = *(const f32x4*)&eps[rl * 66 + c4];
            *(f32x4*)&oz[(size_t)(rb + rl) * HWN + n0 + c4] = v;
        }
    }
}

// ============ KG3F: y = M_b @ v + b_proj, IN-PLACE on d_out; swizzled LDS staging ============
// grid (256 n-tiles of 64, 8 b), block 256 (4 waves; wave = 48 rows x 64 px).
__global__ __launch_bounds__(256, 3) void kg3f(float* __restrict__ vy,
                                               const ushort* __restrict__ Mh,
                                               const ushort* __restrict__ Ml,
                                               const float* __restrict__ bias) {
    __shared__ ushort smem[2 * 64 * 200];
    ushort* BsH = smem;
    ushort* BsL = smem + 64 * 200;
    const int z = blockIdx.y;
    float* vb = vy + (size_t)z * DIMC * HWN;
    const int n0 = blockIdx.x * 64;
    const int tid = threadIdx.x;
#pragma unroll
    for (int it = 0; it < 12; it++) {
        int idx = tid + it * 256;
        int ch = idx >> 4, q = idx & 15;
        f32x4 v = *(const f32x4*)&vb[(size_t)ch * HWN + n0 + q * 4];
        const int swz = ((ch >> 3) ^ (q & 7)) * 8 + (ch & 7);
#pragma unroll
        for (int p = 0; p < 4; p++) {
            int ad = (q * 4 + p) * 200 + swz;
            ushort hb = f2bf(v[p]);
            BsH[ad] = hb;
            BsL[ad] = f2bf(v[p] - bf2f(hb));
        }
    }
    __syncthreads();
    const int wid = tid >> 6, lane = tid & 63;
    const int lr = lane & 15, lk = lane >> 4;
    const int mb = wid * 48;
    const ushort* Azh = Mh + (size_t)z * DIMC * DIMC;
    const ushort* Azl = Ml + (size_t)z * DIMC * DIMC;
    f32x4 acc[3][4];
#pragma unroll
    for (int i = 0; i < 3; i++)
#pragma unroll
        for (int j = 0; j < 4; j++) acc[i][j] = (f32x4)0.f;

    for (int kc6 = 0; kc6 < 6; kc6++) {
        short8 bh[4], bl[4];
#pragma unroll
        for (int j = 0; j < 4; j++) {
            int px = j * 16 + lr;
            int o = (kc6 * 4 + lk) ^ ((px >> 2) & 7);
            int ad = px * 200 + o * 8;
            bh[j] = *(const short8*)&BsH[ad];
            bl[j] = *(const short8*)&BsL[ad];
        }
#pragma unroll
        for (int i = 0; i < 3; i++) {
            size_t ao = (size_t)(mb + i * 16 + lr) * DIMC + kc6 * 32 + lk * 8;
            const short8 ah = *(const short8*)&Azh[ao];
            const short8 al = *(const short8*)&Azl[ao];
#pragma unroll
            for (int j = 0; j < 4; j++) {
                acc[i][j] = __builtin_amdgcn_mfma_f32_16x16x32_bf16(ah, bh[j], acc[i][j], 0, 0, 0);
                acc[i][j] = __builtin_amdgcn_mfma_f32_16x16x32_bf16(ah, bl[j], acc[i][j], 0, 0, 0);
                acc[i][j] = __builtin_amdgcn_mfma_f32_16x16x32_bf16(al, bh[j], acc[i][j], 0, 0, 0);
            }
        }
    }
    __syncthreads();  // all v reads done (LDS holds v); in-place writes + LDS reuse safe
    float* epsb = (float*)smem + wid * (2 * 1056);
#pragma unroll
    for (int i = 0; i < 3; i++) {
        float* eps = epsb + (i & 1) * 1056;
        int rb = mb + i * 16;
#pragma unroll
        for (int j = 0; j < 4; j++)
#pragma unroll
            for (int r = 0; r < 4; r++)
                eps[(lk * 4 + r) * 66 + j * 16 + lr] = acc[i][j][r] + bias[rb + lk * 4 + r];
#pragma unroll
        for (int s = 0; s < 4; s++) {
            int rl = s * 4 + (lane >> 4);
            int c4 = (lane & 15) * 4;
            f32x4 v = *(const f32x4*)&eps[rl * 66 + c4];
            *(f32x4*)&vb[(size_t)(rb + rl) * HWN + n0 + c4] = v;
        }
    }
}

// ============ K2: depthwise 3x3 + Gram/sumsq partials; v -> fp32 d_out ============
// grid (32 stripes of 4 rows, 8 heads, NZ), block 1024 (16 waves).
__global__ __launch_bounds__(1024, 4) void k2_dw(const float* __restrict__ qkv0, long qkv_zs,
                                                 const float* __restrict__ wdw,
                                                 const float* __restrict__ bdw,
                                                 float* __restrict__ vout,
                                                 float* __restrict__ part, int b0) {
    __shared__ float stage[2 * 6336];   // [2][8][6][132]
    __shared__ float qks[48 * 520];     // [qk ch][512 px + pad], fp32
    const int b = b0 + blockIdx.z;
    const float* qkv = qkv0 + (size_t)blockIdx.z * qkv_zs;
    const int stripe = blockIdx.x, h = blockIdx.y;
    const int tid = threadIdx.x;
    const int r0 = stripe * 4;

    const int col4 = (tid & 31) * 4;
    const int orow = (tid >> 5) & 3;
    const int cc = tid >> 7;  // 0..7

    auto stage_load = [&](int chunk, int buf) {
        const int g = chunk / 3, cb = (chunk % 3) * 8;
        float* sb = stage + buf * 6336;
#pragma unroll
        for (int f = tid; f < 1536; f += 1024) {
            int fc = f / 192, rem = f - fc * 192;
            int rl = rem >> 5, c4 = rem & 31;
            int gr = r0 - 1 + rl;
            int ch = g * DIMC + h * CDh + cb + fc;
            float4 v = make_float4(0.f, 0.f, 0.f, 0.f);
            if (gr >= 0 && gr < 128)
                v = *(const float4*)&qkv[(size_t)ch * HWN + gr * WIDTH + c4 * 4];
            *(float4*)&sb[(fc * 6 + rl) * 132 + c4 * 4] = v;
        }
    };

    stage_load(0, 0);
    __syncthreads();
    for (int chunk = 0; chunk < 9; chunk++) {
        const int buf = chunk & 1;
        if (chunk < 8) stage_load(chunk + 1, buf ^ 1);
        const int g = chunk / 3, cb = (chunk % 3) * 8;
        const float* sb = stage + buf * 6336;
        const int ch = g * DIMC + h * CDh + cb + cc;
        float wr[9];
#pragma unroll
        for (int t = 0; t < 9; t++) wr[t] = wdw[ch * 9 + t];
        float bsv = bdw[ch];
        float a0 = bsv, a1 = bsv, a2 = bsv, a3 = bsv;
#pragma unroll
        for (int dr = 0; dr < 3; dr++) {
            const float* row = &sb[(cc * 6 + orow + dr) * 132];
            f32x4 cen = *(const f32x4*)&row[col4];
            f32x4 lf4 = (col4 > 0) ? *(const f32x4*)&row[col4 - 4] : (f32x4)0.f;
            f32x4 rt4 = (col4 < 124) ? *(const f32x4*)&row[col4 + 4] : (f32x4)0.f;
            float left = lf4[3], right = rt4[0];
            float wA = wr[dr * 3 + 0], wB = wr[dr * 3 + 1], wC = wr[dr * 3 + 2];
            a0 = fmaf(left, wA, fmaf(cen[0], wB, fmaf(cen[1], wC, a0)));
            a1 = fmaf(cen[0], wA, fmaf(cen[1], wB, fmaf(cen[2], wC, a1)));
            a2 = fmaf(cen[1], wA, fmaf(cen[2], wB, fmaf(cen[3], wC, a2)));
            a3 = fmaf(cen[2], wA, fmaf(cen[3], wB, fmaf(right, wC, a3)));
        }
        if (g < 2) {
            float4 o4 = {a0, a1, a2, a3};
            *(float4*)&qks[(g * CDh + cb + cc) * 520 + orow * 128 + col4] = o4;
        } else {
            float4 o4 = {a0, a1, a2, a3};
            *(float4*)&vout[((size_t)b * DIMC + h * CDh + cb + cc) * HWN +
                            (size_t)(r0 + orow) * WIDTH + col4] = o4;
        }
        __syncthreads();
    }

    const int tc = tid & 3, td = (tid >> 2) & 3, tp = tid >> 4;
    float ga[6][6];
#pragma unroll
    for (int i = 0; i < 6; i++)
#pragma unroll
        for (int j = 0; j < 6; j++) ga[i][j] = 0.f;
#pragma unroll
    for (int s = 0; s < 2; s++) {
        int px = tp * 8 + s * 4;
        f32x4 qv[6], kv[6];
#pragma unroll
        for (int i = 0; i < 6; i++) qv[i] = *(const f32x4*)&qks[(tc * 6 + i) * 520 + px];
#pragma unroll
        for (int j = 0; j < 6; j++) kv[j] = *(const f32x4*)&qks[(24 + td * 6 + j) * 520 + px];
#pragma unroll
        for (int i = 0; i < 6; i++)
#pragma unroll
            for (int j = 0; j < 6; j++) {
                ga[i][j] = fmaf(qv[i][0], kv[j][0], ga[i][j]);
                ga[i][j] = fmaf(qv[i][1], kv[j][1], ga[i][j]);
                ga[i][j] = fmaf(qv[i][2], kv[j][2], ga[i][j]);
                ga[i][j] = fmaf(qv[i][3], kv[j][3], ga[i][j]);
            }
    }
#pragma unroll
    for (int i = 0; i < 6; i++)
#pragma unroll
        for (int j = 0; j < 6; j++) {
            float v = ga[i][j];
            v += __shfl_xor(v, 16, 64);
            v += __shfl_xor(v, 32, 64);
            ga[i][j] = v;
        }
    float nv = 0.f;
    int nch = 0, npg = 0;
    if (tid < 768) {
        npg = tid / 48;
        nch = tid - npg * 48;
#pragma unroll
        for (int s = 0; s < 8; s++) {
            f32x4 v = *(const f32x4*)&qks[nch * 520 + npg * 32 + s * 4];
            nv = fmaf(v[0], v[0], nv);
            nv = fmaf(v[1], v[1], nv);
            nv = fmaf(v[2], v[2], nv);
            nv = fmaf(v[3], v[3], nv);
        }
    }
    __syncthreads();
    float* gscr = qks;  // [16][624]
    const int wave = tid >> 6;
    if ((tid & 63) < 16) {
#pragma unroll
        for (int i = 0; i < 6; i++)
#pragma unroll
            for (int j = 0; j < 6; j++)
                gscr[wave * 624 + (tc * 6 + i) * 24 + (td * 6 + j)] = ga[i][j];
    }
    if (tid < 768) gscr[npg * 624 + 576 + nch] = nv;
    __syncthreads();
    if (tid < 624) {
        float s = 0.f;
#pragma unroll
        for (int w2 = 0; w2 < 16; w2++) s += gscr[w2 * 624 + tid];
        part[((size_t)(b * NHEADS + h) * 64 + stripe) * 624 + tid] = s;  // coalesced
    }
}

// ============ K34: reduce partials + attn + 4 top-k softmaxes -> A_eff ============
// part layout [bh][64 slots][624]; 32 stripes are real.
__global__ void k34_attn(const float* __restrict__ part, const float* __restrict__ temp,
                         const float* __restrict__ a1, const float* __restrict__ a2,
                         const float* __restrict__ a3, const float* __restrict__ a4,
                         float* __restrict__ Aeff) {
    __shared__ float gbuf[624];
    int bh = blockIdx.x;
    int h = bh & 7;
    int tid = threadIdx.x;
    for (int ti = tid; ti < 624; ti += 256) {
        float s = 0.f;
        const float* p = part + (size_t)bh * 64 * 624 + ti;
#pragma unroll 4
        for (int st = 0; st < 32; st++) s += p[st * 624];
        gbuf[ti] = s;
    }
    __syncthreads();
    int r = tid;
    if (r >= CDh) return;
    float t = temp[h];
    float aw[4] = {a1[0], a2[0], a3[0], a4[0]};
    const int kks[4] = {12, 16, 18, 19};
    float qn = fmaxf(sqrtf(gbuf[576 + r]), 1e-12f);
    float av[24];
    for (int d = 0; d < 24; d++) {
        float kn = fmaxf(sqrtf(gbuf[600 + d]), 1e-12f);
        av[d] = gbuf[r * 24 + d] / (qn * kn) * t;
    }
    int rank[24];
    float m = -1e30f;
    for (int d = 0; d < 24; d++) {
        int rk = 0;
        for (int e = 0; e < 24; e++)
            rk += (av[e] > av[d]) || (av[e] == av[d] && e < d);
        rank[d] = rk;
        m = fmaxf(m, av[d]);
    }
    float ex[24], outv[24];
    for (int d = 0; d < 24; d++) { ex[d] = expf(av[d] - m); outv[d] = 0.f; }
    for (int i = 0; i < 4; i++) {
        float Z = 0.f;
        for (int d = 0; d < 24; d++) if (rank[d] < kks[i]) Z += ex[d];
        float inv = aw[i] / Z;
        for (int d = 0; d < 24; d++) if (rank[d] < kks[i]) outv[d] += ex[d] * inv;
    }
    for (int d = 0; d < 24; d++) Aeff[(bh * 24 + r) * 24 + d] = outv[d];
}

// ============ K4b: M_b = W_proj @ blockdiag(A_eff) -> bf16 hi/lo ============
__global__ void k4b_mmat(const float* __restrict__ Wp, const float* __restrict__ Aeff,
                         ushort* __restrict__ Mh, ushort* __restrict__ Ml) {
    int b = blockIdx.x;
    int e0 = blockIdx.y * 6144;
    for (int e = e0 + threadIdx.x; e < e0 + 6144; e += 256) {
        int o = e / DIMC, j = e % DIMC;
        int h = j / CDh, d = j % CDh;
        const float* wrow = Wp + o * DIMC + h * CDh;
        const float* acol = Aeff + (size_t)((b * NHEADS + h) * CDh) * CDh + d;
        float s = 0.f;
        for (int c = 0; c < CDh; c++) s = fmaf(wrow[c], acol[c * CDh], s);
        size_t idx = ((size_t)b * DIMC + o) * DIMC + j;
        ushort hb = f2bf(s);
        Mh[idx] = hb;
        Ml[idx] = f2bf(s - bf2f(hb));
    }
}

extern "C" void kernel_launch(void* const* d_in, const int* in_sizes, int n_in,
                              void* d_out, int out_size, void* d_ws, size_t ws_size,
                              hipStream_t stream) {
    const float* x     = (const float*)d_in[0];
    const float* wqkv  = (const float*)d_in[1];
    const float* bqkv  = (const float*)d_in[2];
    const float* wdw   = (const float*)d_in[3];
    const float* bdw   = (const float*)d_in[4];
    const float* wproj = (const float*)d_in[5];
    const float* bproj = (const float*)d_in[6];
    const float* temp  = (const float*)d_in[7];
    const float* a1    = (const float*)d_in[8];
    const float* a2    = (const float*)d_in[9];
    const float* a3    = (const float*)d_in[10];
    const float* a4    = (const float*)d_in[11];
    float* out = (float*)d_out;

    float* ws = (float*)d_ws;
    const size_t fl_part = (size_t)64 * 64 * 624;
    const size_t fl_A    = (size_t)64 * 576;
    const size_t fl_M    = (size_t)NBATCH * DIMC * DIMC / 2;
    const size_t fl_W    = (size_t)C3 * DIMC / 2;
    const size_t fl_qkv1 = (size_t)C3 * HWN;
    const size_t base_fl = fl_part + fl_A + 2 * fl_M + 2 * fl_W;

    // nz=2: qkv pair (75.5 MB) stays L3-blocked; halves loop launch count.
    int nz = (ws_size >= (base_fl + 2 * fl_qkv1) * sizeof(float)) ? 2 : 1;

    size_t o = 0;
    float* part = ws + o; o += fl_part;
    float* Aeff = ws + o; o += fl_A;
    ushort* Mh  = (ushort*)(ws + o); o += fl_M;
    ushort* Ml  = (ushort*)(ws + o); o += fl_M;
    ushort* Wh  = (ushort*)(ws + o); o += fl_W;
    ushort* Wl  = (ushort*)(ws + o); o += fl_W;
    float* qkv  = ws + o;

    const long qkv_zs = (long)fl_qkv1;

    k0_prep<<<(C3 * DIMC + 255) / 256, 256, 0, stream>>>(wqkv, Wh, Wl, C3 * DIMC);

    for (int b0 = 0; b0 < NBATCH; b0 += nz) {
        kgx3<<<dim3(256, 3, nz), 256, 0, stream>>>(x + (size_t)b0 * DIMC * HWN,
                                                   Wh, Wl, bqkv, qkv, qkv_zs);
        k2_dw<<<dim3(32, 8, nz), 1024, 0, stream>>>(qkv, qkv_zs, wdw, bdw, out, part, b0);
    }
    k34_attn<<<64, 256, 0, stream>>>(part, temp, a1, a2, a3, a4, Aeff);
    k4b_mmat<<<dim3(8, 6), 256, 0, stream>>>(wproj, Aeff, Mh, Ml);
    kg3f<<<dim3(256, 8), 256, 0, stream>>>(out, Mh, Ml, bproj);
}

// Round 15
// 449.477 us; speedup vs baseline: 1.4453x; 1.0232x over previous
//
#include <hip/hip_runtime.h>
#include <math.h>

#define DIMC 192
#define C3 576
#define NHEADS 8
#define CDh 24
#define HWN 16384
#define WIDTH 128
#define NBATCH 8
#define QKS 524  // qks row stride: 524 mod 32 = 12 -> 8-bank spread (520 was 4)

typedef __attribute__((ext_vector_type(8))) short short8;
typedef __attribute__((ext_vector_type(4))) float f32x4;

__device__ __forceinline__ ushort f2bf(float f) {
    uint u = __float_as_uint(f);
    u += 0x7fff + ((u >> 16) & 1);
    return (ushort)(u >> 16);
}
__device__ __forceinline__ float bf2f(ushort h) {
    return __uint_as_float(((uint)h) << 16);
}

// ============ K0: split W_qkv -> bf16 hi/lo ============
__global__ void k0_prep(const float* __restrict__ W, ushort* __restrict__ Wh,
                        ushort* __restrict__ Wl, int n) {
    int i = blockIdx.x * 256 + threadIdx.x;
    if (i < n) {
        float w = W[i];
        ushort h = f2bf(w);
        Wh[i] = h;
        Wl[i] = f2bf(w - bf2f(h));
    }
}

// ============ KGX3: qkv = W @ x + b via split-bf16 MFMA; x fp32 staged+split in LDS ============
// grid (256 n-tiles of 64 px, 3 m-tiles of 192, NZ), block 256 (4 waves; wave=48r x 64px).
// Linear LDS staging (R13-proven; R14's XOR swizzle cost more in inner-loop VALU than
// it saved in conflicts). unroll 2 on K-loop: prefetch next A-frags under current MFMAs.
__global__ __launch_bounds__(256, 3) void kgx3(const float* __restrict__ x,
                                               const ushort* __restrict__ Wh,
                                               const ushort* __restrict__ Wl,
                                               const float* __restrict__ bias,
                                               float* __restrict__ qkv, long qkv_zs) {
    __shared__ ushort smem[2 * 64 * 200];  // B-stage hi/lo; reused as f32 epilogue buf
    ushort* BsH = smem;
    ushort* BsL = smem + 64 * 200;
    const float* xb = x + (size_t)blockIdx.z * DIMC * HWN;
    float* oz = qkv + (size_t)blockIdx.z * qkv_zs;
    const int n0 = blockIdx.x * 64;
    const int o0 = blockIdx.y * 192;
    const int tid = threadIdx.x;
#pragma unroll
    for (int it = 0; it < 12; it++) {
        int idx = tid + it * 256;
        int ch = idx >> 4, q = idx & 15;
        f32x4 v = *(const f32x4*)&xb[(size_t)ch * HWN + n0 + q * 4];
#pragma unroll
        for (int p = 0; p < 4; p++) {
            int ad = (q * 4 + p) * 200 + ch;
            ushort hb = f2bf(v[p]);
            BsH[ad] = hb;
            BsL[ad] = f2bf(v[p] - bf2f(hb));
        }
    }
    __syncthreads();
    const int wid = tid >> 6, lane = tid & 63;
    const int lr = lane & 15, lk = lane >> 4;
    const int mb = o0 + wid * 48;
    f32x4 acc[3][4];
#pragma unroll
    for (int i = 0; i < 3; i++)
#pragma unroll
        for (int j = 0; j < 4; j++) acc[i][j] = (f32x4)0.f;

#pragma unroll 2
    for (int kc6 = 0; kc6 < 6; kc6++) {
        short8 bh[4], bl[4];
#pragma unroll
        for (int j = 0; j < 4; j++) {
            int ad = (j * 16 + lr) * 200 + kc6 * 32 + lk * 8;
            bh[j] = *(const short8*)&BsH[ad];
            bl[j] = *(const short8*)&BsL[ad];
        }
#pragma unroll
        for (int i = 0; i < 3; i++) {
            size_t ao = (size_t)(mb + i * 16 + lr) * DIMC + kc6 * 32 + lk * 8;
            const short8 ah = *(const short8*)&Wh[ao];
            const short8 al = *(const short8*)&Wl[ao];
#pragma unroll
            for (int j = 0; j < 4; j++) {
                acc[i][j] = __builtin_amdgcn_mfma_f32_16x16x32_bf16(ah, bh[j], acc[i][j], 0, 0, 0);
                acc[i][j] = __builtin_amdgcn_mfma_f32_16x16x32_bf16(ah, bl[j], acc[i][j], 0, 0, 0);
                acc[i][j] = __builtin_amdgcn_mfma_f32_16x16x32_bf16(al, bh[j], acc[i][j], 0, 0, 0);
            }
        }
    }
    __syncthreads();  // all waves done reading BsH/BsL -> reuse as epilogue staging
    float* epsb = (float*)smem + wid * (2 * 1056);  // per-wave double buffer [2][16][66]
#pragma unroll
    for (int i = 0; i < 3; i++) {
        float* eps = epsb + (i & 1) * 1056;
        int rb = mb + i * 16;
#pragma unroll
        for (int j = 0; j < 4; j++)
#pragma unroll
            for (int r = 0; r < 4; r++)
                eps[(lk * 4 + r) * 66 + j * 16 + lr] = acc[i][j][r] + bias[rb + lk * 4 + r];
#pragma unroll
        for (int s = 0; s < 4; s++) {
            int rl = s * 4 + (lane >> 4);
            int c4 = (lane & 15) * 4;
            f32x4 v = *(const f32x4*)&eps[rl * 66 + c4];
            *(f32x4*)&oz[(size_t)(rb + rl) * HWN + n0 + c4] = v;
        }
    }
}

// ============ KG3F: y = M_b @ v + b_proj, IN-PLACE on d_out; v fp32 staged+split in LDS ============
// grid (256 n-tiles of 64, 8 b), block 256 (4 waves; wave = 48 rows x 64 px).
__global__ __launch_bounds__(256, 3) void kg3f(float* __restrict__ vy,
                                               const ushort* __restrict__ Mh,
                                               const ushort* __restrict__ Ml,
                                               const float* __restrict__ bias) {
    __shared__ ushort smem[2 * 64 * 200];
    ushort* BsH = smem;
    ushort* BsL = smem + 64 * 200;
    const int z = blockIdx.y;
    float* vb = vy + (size_t)z * DIMC * HWN;
    const int n0 = blockIdx.x * 64;
    const int tid = threadIdx.x;
#pragma unroll
    for (int it = 0; it < 12; it++) {
        int idx = tid + it * 256;
        int ch = idx >> 4, q = idx & 15;
        f32x4 v = *(const f32x4*)&vb[(size_t)ch * HWN + n0 + q * 4];
#pragma unroll
        for (int p = 0; p < 4; p++) {
            int ad = (q * 4 + p) * 200 + ch;
            ushort hb = f2bf(v[p]);
            BsH[ad] = hb;
            BsL[ad] = f2bf(v[p] - bf2f(hb));
        }
    }
    __syncthreads();
    const int wid = tid >> 6, lane = tid & 63;
    const int lr = lane & 15, lk = lane >> 4;
    const int mb = wid * 48;
    const ushort* Azh = Mh + (size_t)z * DIMC * DIMC;
    const ushort* Azl = Ml + (size_t)z * DIMC * DIMC;
    f32x4 acc[3][4];
#pragma unroll
    for (int i = 0; i < 3; i++)
#pragma unroll
        for (int j = 0; j < 4; j++) acc[i][j] = (f32x4)0.f;

#pragma unroll 2
    for (int kc6 = 0; kc6 < 6; kc6++) {
        short8 bh[4], bl[4];
#pragma unroll
        for (int j = 0; j < 4; j++) {
            int ad = (j * 16 + lr) * 200 + kc6 * 32 + lk * 8;
            bh[j] = *(const short8*)&BsH[ad];
            bl[j] = *(const short8*)&BsL[ad];
        }
#pragma unroll
        for (int i = 0; i < 3; i++) {
            size_t ao = (size_t)(mb + i * 16 + lr) * DIMC + kc6 * 32 + lk * 8;
            const short8 ah = *(const short8*)&Azh[ao];
            const short8 al = *(const short8*)&Azl[ao];
#pragma unroll
            for (int j = 0; j < 4; j++) {
                acc[i][j] = __builtin_amdgcn_mfma_f32_16x16x32_bf16(ah, bh[j], acc[i][j], 0, 0, 0);
                acc[i][j] = __builtin_amdgcn_mfma_f32_16x16x32_bf16(ah, bl[j], acc[i][j], 0, 0, 0);
                acc[i][j] = __builtin_amdgcn_mfma_f32_16x16x32_bf16(al, bh[j], acc[i][j], 0, 0, 0);
            }
        }
    }
    __syncthreads();  // all v reads done (LDS holds v); in-place writes + LDS reuse safe
    float* epsb = (float*)smem + wid * (2 * 1056);
#pragma unroll
    for (int i = 0; i < 3; i++) {
        float* eps = epsb + (i & 1) * 1056;
        int rb = mb + i * 16;
#pragma unroll
        for (int j = 0; j < 4; j++)
#pragma unroll
            for (int r = 0; r < 4; r++)
                eps[(lk * 4 + r) * 66 + j * 16 + lr] = acc[i][j][r] + bias[rb + lk * 4 + r];
#pragma unroll
        for (int s = 0; s < 4; s++) {
            int rl = s * 4 + (lane >> 4);
            int c4 = (lane & 15) * 4;
            f32x4 v = *(const f32x4*)&eps[rl * 66 + c4];
            *(f32x4*)&vb[(size_t)(rb + rl) * HWN + n0 + c4] = v;
        }
    }
}

// ============ K2: depthwise 3x3 + Gram/sumsq partials; v -> fp32 d_out ============
// grid (32 stripes of 4 rows, 8 heads, NZ), block 1024 (16 waves).
__global__ __launch_bounds__(1024, 4) void k2_dw(const float* __restrict__ qkv0, long qkv_zs,
                                                 const float* __restrict__ wdw,
                                                 const float* __restrict__ bdw,
                                                 float* __restrict__ vout,
                                                 float* __restrict__ part, int b0) {
    __shared__ float stage[2 * 6336];   // [2][8][6][132]
    __shared__ float qks[48 * QKS];     // [qk ch][512 px + pad], fp32
    const int b = b0 + blockIdx.z;
    const float* qkv = qkv0 + (size_t)blockIdx.z * qkv_zs;
    const int stripe = blockIdx.x, h = blockIdx.y;
    const int tid = threadIdx.x;
    const int r0 = stripe * 4;

    const int col4 = (tid & 31) * 4;
    const int orow = (tid >> 5) & 3;
    const int cc = tid >> 7;  // 0..7

    auto stage_load = [&](int chunk, int buf) {
        const int g = chunk / 3, cb = (chunk % 3) * 8;
        float* sb = stage + buf * 6336;
#pragma unroll
        for (int f = tid; f < 1536; f += 1024) {
            int fc = f / 192, rem = f - fc * 192;
            int rl = rem >> 5, c4 = rem & 31;
            int gr = r0 - 1 + rl;
            int ch = g * DIMC + h * CDh + cb + fc;
            float4 v = make_float4(0.f, 0.f, 0.f, 0.f);
            if (gr >= 0 && gr < 128)
                v = *(const float4*)&qkv[(size_t)ch * HWN + gr * WIDTH + c4 * 4];
            *(float4*)&sb[(fc * 6 + rl) * 132 + c4 * 4] = v;
        }
    };

    stage_load(0, 0);
    __syncthreads();
    for (int chunk = 0; chunk < 9; chunk++) {
        const int buf = chunk & 1;
        if (chunk < 8) stage_load(chunk + 1, buf ^ 1);
        const int g = chunk / 3, cb = (chunk % 3) * 8;
        const float* sb = stage + buf * 6336;
        const int ch = g * DIMC + h * CDh + cb + cc;
        float wr[9];
#pragma unroll
        for (int t = 0; t < 9; t++) wr[t] = wdw[ch * 9 + t];
        float bsv = bdw[ch];
        float a0 = bsv, a1 = bsv, a2 = bsv, a3 = bsv;
#pragma unroll
        for (int dr = 0; dr < 3; dr++) {
            const float* row = &sb[(cc * 6 + orow + dr) * 132];
            f32x4 cen = *(const f32x4*)&row[col4];
            f32x4 lf4 = (col4 > 0) ? *(const f32x4*)&row[col4 - 4] : (f32x4)0.f;
            f32x4 rt4 = (col4 < 124) ? *(const f32x4*)&row[col4 + 4] : (f32x4)0.f;
            float left = lf4[3], right = rt4[0];
            float wA = wr[dr * 3 + 0], wB = wr[dr * 3 + 1], wC = wr[dr * 3 + 2];
            a0 = fmaf(left, wA, fmaf(cen[0], wB, fmaf(cen[1], wC, a0)));
            a1 = fmaf(cen[0], wA, fmaf(cen[1], wB, fmaf(cen[2], wC, a1)));
            a2 = fmaf(cen[1], wA, fmaf(cen[2], wB, fmaf(cen[3], wC, a2)));
            a3 = fmaf(cen[2], wA, fmaf(cen[3], wB, fmaf(right, wC, a3)));
        }
        if (g < 2) {
            float4 o4 = {a0, a1, a2, a3};
            *(float4*)&qks[(g * CDh + cb + cc) * QKS + orow * 128 + col4] = o4;
        } else {
            float4 o4 = {a0, a1, a2, a3};
            *(float4*)&vout[((size_t)b * DIMC + h * CDh + cb + cc) * HWN +
                            (size_t)(r0 + orow) * WIDTH + col4] = o4;
        }
        __syncthreads();
    }

    const int tc = tid & 3, td = (tid >> 2) & 3, tp = tid >> 4;
    float ga[6][6];
#pragma unroll
    for (int i = 0; i < 6; i++)
#pragma unroll
        for (int j = 0; j < 6; j++) ga[i][j] = 0.f;
#pragma unroll
    for (int s = 0; s < 2; s++) {
        int px = tp * 8 + s * 4;
        f32x4 qv[6], kv[6];
#pragma unroll
        for (int i = 0; i < 6; i++) qv[i] = *(const f32x4*)&qks[(tc * 6 + i) * QKS + px];
#pragma unroll
        for (int j = 0; j < 6; j++) kv[j] = *(const f32x4*)&qks[(24 + td * 6 + j) * QKS + px];
#pragma unroll
        for (int i = 0; i < 6; i++)
#pragma unroll
            for (int j = 0; j < 6; j++) {
                ga[i][j] = fmaf(qv[i][0], kv[j][0], ga[i][j]);
                ga[i][j] = fmaf(qv[i][1], kv[j][1], ga[i][j]);
                ga[i][j] = fmaf(qv[i][2], kv[j][2], ga[i][j]);
                ga[i][j] = fmaf(qv[i][3], kv[j][3], ga[i][j]);
            }
    }
#pragma unroll
    for (int i = 0; i < 6; i++)
#pragma unroll
        for (int j = 0; j < 6; j++) {
            float v = ga[i][j];
            v += __shfl_xor(v, 16, 64);
            v += __shfl_xor(v, 32, 64);
            ga[i][j] = v;
        }
    float nv = 0.f;
    int nch = 0, npg = 0;
    if (tid < 768) {
        npg = tid / 48;
        nch = tid - npg * 48;
#pragma unroll
        for (int s = 0; s < 8; s++) {
            f32x4 v = *(const f32x4*)&qks[nch * QKS + npg * 32 + s * 4];
            nv = fmaf(v[0], v[0], nv);
            nv = fmaf(v[1], v[1], nv);
            nv = fmaf(v[2], v[2], nv);
            nv = fmaf(v[3], v[3], nv);
        }
    }
    __syncthreads();
    float* gscr = qks;  // [16][624]
    const int wave = tid >> 6;
    if ((tid & 63) < 16) {
#pragma unroll
        for (int i = 0; i < 6; i++)
#pragma unroll
            for (int j = 0; j < 6; j++)
                gscr[wave * 624 + (tc * 6 + i) * 24 + (td * 6 + j)] = ga[i][j];
    }
    if (tid < 768) gscr[npg * 624 + 576 + nch] = nv;
    __syncthreads();
    if (tid < 624) {
        float s = 0.f;
#pragma unroll
        for (int w2 = 0; w2 < 16; w2++) s += gscr[w2 * 624 + tid];
        part[((size_t)(b * NHEADS + h) * 64 + stripe) * 624 + tid] = s;  // coalesced
    }
}

// ============ K34: reduce partials + attn + 4 top-k softmaxes -> A_eff ============
// part layout [bh][64 slots][624]; 32 stripes are real.
__global__ void k34_attn(const float* __restrict__ part, const float* __restrict__ temp,
                         const float* __restrict__ a1, const float* __restrict__ a2,
                         const float* __restrict__ a3, const float* __restrict__ a4,
                         float* __restrict__ Aeff) {
    __shared__ float gbuf[624];
    int bh = blockIdx.x;
    int h = bh & 7;
    int tid = threadIdx.x;
    for (int ti = tid; ti < 624; ti += 256) {
        float s = 0.f;
        const float* p = part + (size_t)bh * 64 * 624 + ti;
#pragma unroll 4
        for (int st = 0; st < 32; st++) s += p[st * 624];
        gbuf[ti] = s;
    }
    __syncthreads();
    int r = tid;
    if (r >= CDh) return;
    float t = temp[h];
    float aw[4] = {a1[0], a2[0], a3[0], a4[0]};
    const int kks[4] = {12, 16, 18, 19};
    float qn = fmaxf(sqrtf(gbuf[576 + r]), 1e-12f);
    float av[24];
    for (int d = 0; d < 24; d++) {
        float kn = fmaxf(sqrtf(gbuf[600 + d]), 1e-12f);
        av[d] = gbuf[r * 24 + d] / (qn * kn) * t;
    }
    int rank[24];
    float m = -1e30f;
    for (int d = 0; d < 24; d++) {
        int rk = 0;
        for (int e = 0; e < 24; e++)
            rk += (av[e] > av[d]) || (av[e] == av[d] && e < d);
        rank[d] = rk;
        m = fmaxf(m, av[d]);
    }
    float ex[24], outv[24];
    for (int d = 0; d < 24; d++) { ex[d] = expf(av[d] - m); outv[d] = 0.f; }
    for (int i = 0; i < 4; i++) {
        float Z = 0.f;
        for (int d = 0; d < 24; d++) if (rank[d] < kks[i]) Z += ex[d];
        float inv = aw[i] / Z;
        for (int d = 0; d < 24; d++) if (rank[d] < kks[i]) outv[d] += ex[d] * inv;
    }
    for (int d = 0; d < 24; d++) Aeff[(bh * 24 + r) * 24 + d] = outv[d];
}

// ============ K4b: M_b = W_proj @ blockdiag(A_eff) -> bf16 hi/lo ============
__global__ void k4b_mmat(const float* __restrict__ Wp, const float* __restrict__ Aeff,
                         ushort* __restrict__ Mh, ushort* __restrict__ Ml) {
    int b = blockIdx.x;
    int e0 = blockIdx.y * 6144;
    for (int e = e0 + threadIdx.x; e < e0 + 6144; e += 256) {
        int o = e / DIMC, j = e % DIMC;
        int h = j / CDh, d = j % CDh;
        const float* wrow = Wp + o * DIMC + h * CDh;
        const float* acol = Aeff + (size_t)((b * NHEADS + h) * CDh) * CDh + d;
        float s = 0.f;
        for (int c = 0; c < CDh; c++) s = fmaf(wrow[c], acol[c * CDh], s);
        size_t idx = ((size_t)b * DIMC + o) * DIMC + j;
        ushort hb = f2bf(s);
        Mh[idx] = hb;
        Ml[idx] = f2bf(s - bf2f(hb));
    }
}

extern "C" void kernel_launch(void* const* d_in, const int* in_sizes, int n_in,
                              void* d_out, int out_size, void* d_ws, size_t ws_size,
                              hipStream_t stream) {
    const float* x     = (const float*)d_in[0];
    const float* wqkv  = (const float*)d_in[1];
    const float* bqkv  = (const float*)d_in[2];
    const float* wdw   = (const float*)d_in[3];
    const float* bdw   = (const float*)d_in[4];
    const float* wproj = (const float*)d_in[5];
    const float* bproj = (const float*)d_in[6];
    const float* temp  = (const float*)d_in[7];
    const float* a1    = (const float*)d_in[8];
    const float* a2    = (const float*)d_in[9];
    const float* a3    = (const float*)d_in[10];
    const float* a4    = (const float*)d_in[11];
    float* out = (float*)d_out;

    float* ws = (float*)d_ws;
    const size_t fl_part = (size_t)64 * 64 * 624;
    const size_t fl_A    = (size_t)64 * 576;
    const size_t fl_M    = (size_t)NBATCH * DIMC * DIMC / 2;
    const size_t fl_W    = (size_t)C3 * DIMC / 2;
    const size_t fl_qkv1 = (size_t)C3 * HWN;
    const size_t base_fl = fl_part + fl_A + 2 * fl_M + 2 * fl_W;

    int nz = 1;
    if (ws_size >= (base_fl + 4 * fl_qkv1) * sizeof(float))      nz = 4;
    else if (ws_size >= (base_fl + 2 * fl_qkv1) * sizeof(float)) nz = 2;

    size_t o = 0;
    float* part = ws + o; o += fl_part;
    float* Aeff = ws + o; o += fl_A;
    ushort* Mh  = (ushort*)(ws + o); o += fl_M;
    ushort* Ml  = (ushort*)(ws + o); o += fl_M;
    ushort* Wh  = (ushort*)(ws + o); o += fl_W;
    ushort* Wl  = (ushort*)(ws + o); o += fl_W;
    float* qkv  = ws + o;

    const long qkv_zs = (long)fl_qkv1;

    k0_prep<<<(C3 * DIMC + 255) / 256, 256, 0, stream>>>(wqkv, Wh, Wl, C3 * DIMC);

    for (int b0 = 0; b0 < NBATCH; b0 += nz) {
        kgx3<<<dim3(256, 3, nz), 256, 0, stream>>>(x + (size_t)b0 * DIMC * HWN,
                                                   Wh, Wl, bqkv, qkv, qkv_zs);
        k2_dw<<<dim3(32, 8, nz), 1024, 0, stream>>>(qkv, qkv_zs, wdw, bdw, out, part, b0);
    }
    k34_attn<<<64, 256, 0, stream>>>(part, temp, a1, a2, a3, a4, Aeff);
    k4b_mmat<<<dim3(8, 6), 256, 0, stream>>>(wproj, Aeff, Mh, Ml);
    kg3f<<<dim3(256, 8), 256, 0, stream>>>(out, Mh, Ml, bproj);
}

// Round 16
// 448.967 us; speedup vs baseline: 1.4469x; 1.0011x over previous
//
#include <hip/hip_runtime.h>
#include <math.h>

#define DIMC 192
#define C3 576
#define NHEADS 8
#define CDh 24
#define HWN 16384
#define WIDTH 128
#define NBATCH 8
#define QKS 524  // qks row stride: 524 mod 32 = 12 -> 8-bank spread (520 was 4)

typedef __attribute__((ext_vector_type(8))) short short8;
typedef __attribute__((ext_vector_type(4))) float f32x4;

__device__ __forceinline__ ushort f2bf(float f) {
    uint u = __float_as_uint(f);
    u += 0x7fff + ((u >> 16) & 1);
    return (ushort)(u >> 16);
}
__device__ __forceinline__ float bf2f(ushort h) {
    return __uint_as_float(((uint)h) << 16);
}

// ============ K0: split W_qkv -> bf16 hi/lo ============
__global__ void k0_prep(const float* __restrict__ W, ushort* __restrict__ Wh,
                        ushort* __restrict__ Wl, int n) {
    int i = blockIdx.x * 256 + threadIdx.x;
    if (i < n) {
        float w = W[i];
        ushort h = f2bf(w);
        Wh[i] = h;
        Wl[i] = f2bf(w - bf2f(h));
    }
}

// Transposed staging: thread owns px=tid&63 and 8 consecutive ch per iteration.
// Same [px][200] LDS layout and contents as before (reads untouched); write
// instructions drop from 8x16-way to 2x8-way conflict per iteration.
__device__ __forceinline__ void stage_split(const float* __restrict__ src,
                                            ushort* __restrict__ BsH,
                                            ushort* __restrict__ BsL,
                                            int n0, int tid) {
    const int px = tid & 63;
    const int cg = tid >> 6;
#pragma unroll
    for (int it = 0; it < 6; it++) {
        const int ch0 = (it * 4 + cg) * 8;
        uint uh[4], ul[4];
#pragma unroll
        for (int c2 = 0; c2 < 4; c2++) {
            float v0 = src[(size_t)(ch0 + 2 * c2) * HWN + n0 + px];
            float v1 = src[(size_t)(ch0 + 2 * c2 + 1) * HWN + n0 + px];
            ushort h0 = f2bf(v0), h1 = f2bf(v1);
            ushort l0 = f2bf(v0 - bf2f(h0)), l1 = f2bf(v1 - bf2f(h1));
            uh[c2] = (uint)h0 | ((uint)h1 << 16);
            ul[c2] = (uint)l0 | ((uint)l1 << 16);
        }
        *(uint4*)&BsH[px * 200 + ch0] = make_uint4(uh[0], uh[1], uh[2], uh[3]);
        *(uint4*)&BsL[px * 200 + ch0] = make_uint4(ul[0], ul[1], ul[2], ul[3]);
    }
}

// ============ KGX3: qkv = W @ x + b via split-bf16 MFMA; x fp32 staged+split in LDS ============
// grid (256 n-tiles of 64 px, 3 m-tiles of 192, NZ), block 256 (4 waves; wave=48r x 64px).
__global__ __launch_bounds__(256, 3) void kgx3(const float* __restrict__ x,
                                               const ushort* __restrict__ Wh,
                                               const ushort* __restrict__ Wl,
                                               const float* __restrict__ bias,
                                               float* __restrict__ qkv, long qkv_zs) {
    __shared__ ushort smem[2 * 64 * 200];  // B-stage hi/lo; reused as f32 epilogue buf
    ushort* BsH = smem;
    ushort* BsL = smem + 64 * 200;
    const float* xb = x + (size_t)blockIdx.z * DIMC * HWN;
    float* oz = qkv + (size_t)blockIdx.z * qkv_zs;
    const int n0 = blockIdx.x * 64;
    const int o0 = blockIdx.y * 192;
    const int tid = threadIdx.x;
    stage_split(xb, BsH, BsL, n0, tid);
    __syncthreads();
    const int wid = tid >> 6, lane = tid & 63;
    const int lr = lane & 15, lk = lane >> 4;
    const int mb = o0 + wid * 48;
    f32x4 acc[3][4];
#pragma unroll
    for (int i = 0; i < 3; i++)
#pragma unroll
        for (int j = 0; j < 4; j++) acc[i][j] = (f32x4)0.f;

#pragma unroll 2
    for (int kc6 = 0; kc6 < 6; kc6++) {
        short8 bh[4], bl[4];
#pragma unroll
        for (int j = 0; j < 4; j++) {
            int ad = (j * 16 + lr) * 200 + kc6 * 32 + lk * 8;
            bh[j] = *(const short8*)&BsH[ad];
            bl[j] = *(const short8*)&BsL[ad];
        }
#pragma unroll
        for (int i = 0; i < 3; i++) {
            size_t ao = (size_t)(mb + i * 16 + lr) * DIMC + kc6 * 32 + lk * 8;
            const short8 ah = *(const short8*)&Wh[ao];
            const short8 al = *(const short8*)&Wl[ao];
#pragma unroll
            for (int j = 0; j < 4; j++) {
                acc[i][j] = __builtin_amdgcn_mfma_f32_16x16x32_bf16(ah, bh[j], acc[i][j], 0, 0, 0);
                acc[i][j] = __builtin_amdgcn_mfma_f32_16x16x32_bf16(ah, bl[j], acc[i][j], 0, 0, 0);
                acc[i][j] = __builtin_amdgcn_mfma_f32_16x16x32_bf16(al, bh[j], acc[i][j], 0, 0, 0);
            }
        }
    }
    __syncthreads();  // all waves done reading BsH/BsL -> reuse as epilogue staging
    float* epsb = (float*)smem + wid * (2 * 1056);  // per-wave double buffer [2][16][66]
#pragma unroll
    for (int i = 0; i < 3; i++) {
        float* eps = epsb + (i & 1) * 1056;
        int rb = mb + i * 16;
#pragma unroll
        for (int j = 0; j < 4; j++)
#pragma unroll
            for (int r = 0; r < 4; r++)
                eps[(lk * 4 + r) * 66 + j * 16 + lr] = acc[i][j][r] + bias[rb + lk * 4 + r];
#pragma unroll
        for (int s = 0; s < 4; s++) {
            int rl = s * 4 + (lane >> 4);
            int c4 = (lane & 15) * 4;
            f32x4 v = *(const f32x4*)&eps[rl * 66 + c4];
            *(f32x4*)&oz[(size_t)(rb + rl) * HWN + n0 + c4] = v;
        }
    }
}

// ============ KG3F: y = M_b @ v + b_proj, IN-PLACE on d_out; v fp32 staged+split in LDS ============
// grid (256 n-tiles of 64, 8 b), block 256 (4 waves; wave = 48 rows x 64 px).
__global__ __launch_bounds__(256, 3) void kg3f(float* __restrict__ vy,
                                               const ushort* __restrict__ Mh,
                                               const ushort* __restrict__ Ml,
                                               const float* __restrict__ bias) {
    __shared__ ushort smem[2 * 64 * 200];
    ushort* BsH = smem;
    ushort* BsL = smem + 64 * 200;
    const int z = blockIdx.y;
    float* vb = vy + (size_t)z * DIMC * HWN;
    const int n0 = blockIdx.x * 64;
    const int tid = threadIdx.x;
    stage_split(vb, BsH, BsL, n0, tid);
    __syncthreads();
    const int wid = tid >> 6, lane = tid & 63;
    const int lr = lane & 15, lk = lane >> 4;
    const int mb = wid * 48;
    const ushort* Azh = Mh + (size_t)z * DIMC * DIMC;
    const ushort* Azl = Ml + (size_t)z * DIMC * DIMC;
    f32x4 acc[3][4];
#pragma unroll
    for (int i = 0; i < 3; i++)
#pragma unroll
        for (int j = 0; j < 4; j++) acc[i][j] = (f32x4)0.f;

#pragma unroll 2
    for (int kc6 = 0; kc6 < 6; kc6++) {
        short8 bh[4], bl[4];
#pragma unroll
        for (int j = 0; j < 4; j++) {
            int ad = (j * 16 + lr) * 200 + kc6 * 32 + lk * 8;
            bh[j] = *(const short8*)&BsH[ad];
            bl[j] = *(const short8*)&BsL[ad];
        }
#pragma unroll
        for (int i = 0; i < 3; i++) {
            size_t ao = (size_t)(mb + i * 16 + lr) * DIMC + kc6 * 32 + lk * 8;
            const short8 ah = *(const short8*)&Azh[ao];
            const short8 al = *(const short8*)&Azl[ao];
#pragma unroll
            for (int j = 0; j < 4; j++) {
                acc[i][j] = __builtin_amdgcn_mfma_f32_16x16x32_bf16(ah, bh[j], acc[i][j], 0, 0, 0);
                acc[i][j] = __builtin_amdgcn_mfma_f32_16x16x32_bf16(ah, bl[j], acc[i][j], 0, 0, 0);
                acc[i][j] = __builtin_amdgcn_mfma_f32_16x16x32_bf16(al, bh[j], acc[i][j], 0, 0, 0);
            }
        }
    }
    __syncthreads();  // all v reads done (LDS holds v); in-place writes + LDS reuse safe
    float* epsb = (float*)smem + wid * (2 * 1056);
#pragma unroll
    for (int i = 0; i < 3; i++) {
        float* eps = epsb + (i & 1) * 1056;
        int rb = mb + i * 16;
#pragma unroll
        for (int j = 0; j < 4; j++)
#pragma unroll
            for (int r = 0; r < 4; r++)
                eps[(lk * 4 + r) * 66 + j * 16 + lr] = acc[i][j][r] + bias[rb + lk * 4 + r];
#pragma unroll
        for (int s = 0; s < 4; s++) {
            int rl = s * 4 + (lane >> 4);
            int c4 = (lane & 15) * 4;
            f32x4 v = *(const f32x4*)&eps[rl * 66 + c4];
            *(f32x4*)&vb[(size_t)(rb + rl) * HWN + n0 + c4] = v;
        }
    }
}

// ============ K2: depthwise 3x3 + Gram/sumsq partials; v -> fp32 d_out ============
// grid (32 stripes of 4 rows, 8 heads, NZ), block 1024 (16 waves).
__global__ __launch_bounds__(1024, 4) void k2_dw(const float* __restrict__ qkv0, long qkv_zs,
                                                 const float* __restrict__ wdw,
                                                 const float* __restrict__ bdw,
                                                 float* __restrict__ vout,
                                                 float* __restrict__ part, int b0) {
    __shared__ float stage[2 * 6336];   // [2][8][6][132]
    __shared__ float qks[48 * QKS];     // [qk ch][512 px + pad], fp32
    const int b = b0 + blockIdx.z;
    const float* qkv = qkv0 + (size_t)blockIdx.z * qkv_zs;
    const int stripe = blockIdx.x, h = blockIdx.y;
    const int tid = threadIdx.x;
    const int r0 = stripe * 4;

    const int col4 = (tid & 31) * 4;
    const int orow = (tid >> 5) & 3;
    const int cc = tid >> 7;  // 0..7

    auto stage_load = [&](int chunk, int buf) {
        const int g = chunk / 3, cb = (chunk % 3) * 8;
        float* sb = stage + buf * 6336;
#pragma unroll
        for (int f = tid; f < 1536; f += 1024) {
            int fc = f / 192, rem = f - fc * 192;
            int rl = rem >> 5, c4 = rem & 31;
            int gr = r0 - 1 + rl;
            int ch = g * DIMC + h * CDh + cb + fc;
            float4 v = make_float4(0.f, 0.f, 0.f, 0.f);
            if (gr >= 0 && gr < 128)
                v = *(const float4*)&qkv[(size_t)ch * HWN + gr * WIDTH + c4 * 4];
            *(float4*)&sb[(fc * 6 + rl) * 132 + c4 * 4] = v;
        }
    };

    stage_load(0, 0);
    __syncthreads();
    for (int chunk = 0; chunk < 9; chunk++) {
        const int buf = chunk & 1;
        if (chunk < 8) stage_load(chunk + 1, buf ^ 1);
        const int g = chunk / 3, cb = (chunk % 3) * 8;
        const float* sb = stage + buf * 6336;
        const int ch = g * DIMC + h * CDh + cb + cc;
        float wr[9];
#pragma unroll
        for (int t = 0; t < 9; t++) wr[t] = wdw[ch * 9 + t];
        float bsv = bdw[ch];
        float a0 = bsv, a1 = bsv, a2 = bsv, a3 = bsv;
#pragma unroll
        for (int dr = 0; dr < 3; dr++) {
            const float* row = &sb[(cc * 6 + orow + dr) * 132];
            f32x4 cen = *(const f32x4*)&row[col4];
            f32x4 lf4 = (col4 > 0) ? *(const f32x4*)&row[col4 - 4] : (f32x4)0.f;
            f32x4 rt4 = (col4 < 124) ? *(const f32x4*)&row[col4 + 4] : (f32x4)0.f;
            float left = lf4[3], right = rt4[0];
            float wA = wr[dr * 3 + 0], wB = wr[dr * 3 + 1], wC = wr[dr * 3 + 2];
            a0 = fmaf(left, wA, fmaf(cen[0], wB, fmaf(cen[1], wC, a0)));
            a1 = fmaf(cen[0], wA, fmaf(cen[1], wB, fmaf(cen[2], wC, a1)));
            a2 = fmaf(cen[1], wA, fmaf(cen[2], wB, fmaf(cen[3], wC, a2)));
            a3 = fmaf(cen[2], wA, fmaf(cen[3], wB, fmaf(right, wC, a3)));
        }
        if (g < 2) {
            float4 o4 = {a0, a1, a2, a3};
            *(float4*)&qks[(g * CDh + cb + cc) * QKS + orow * 128 + col4] = o4;
        } else {
            float4 o4 = {a0, a1, a2, a3};
            *(float4*)&vout[((size_t)b * DIMC + h * CDh + cb + cc) * HWN +
                            (size_t)(r0 + orow) * WIDTH + col4] = o4;
        }
        __syncthreads();
    }

    const int tc = tid & 3, td = (tid >> 2) & 3, tp = tid >> 4;
    float ga[6][6];
#pragma unroll
    for (int i = 0; i < 6; i++)
#pragma unroll
        for (int j = 0; j < 6; j++) ga[i][j] = 0.f;
#pragma unroll
    for (int s = 0; s < 2; s++) {
        int px = tp * 8 + s * 4;
        f32x4 qv[6], kv[6];
#pragma unroll
        for (int i = 0; i < 6; i++) qv[i] = *(const f32x4*)&qks[(tc * 6 + i) * QKS + px];
#pragma unroll
        for (int j = 0; j < 6; j++) kv[j] = *(const f32x4*)&qks[(24 + td * 6 + j) * QKS + px];
#pragma unroll
        for (int i = 0; i < 6; i++)
#pragma unroll
            for (int j = 0; j < 6; j++) {
                ga[i][j] = fmaf(qv[i][0], kv[j][0], ga[i][j]);
                ga[i][j] = fmaf(qv[i][1], kv[j][1], ga[i][j]);
                ga[i][j] = fmaf(qv[i][2], kv[j][2], ga[i][j]);
                ga[i][j] = fmaf(qv[i][3], kv[j][3], ga[i][j]);
            }
    }
#pragma unroll
    for (int i = 0; i < 6; i++)
#pragma unroll
        for (int j = 0; j < 6; j++) {
            float v = ga[i][j];
            v += __shfl_xor(v, 16, 64);
            v += __shfl_xor(v, 32, 64);
            ga[i][j] = v;
        }
    float nv = 0.f;
    int nch = 0, npg = 0;
    if (tid < 768) {
        npg = tid / 48;
        nch = tid - npg * 48;
#pragma unroll
        for (int s = 0; s < 8; s++) {
            f32x4 v = *(const f32x4*)&qks[nch * QKS + npg * 32 + s * 4];
            nv = fmaf(v[0], v[0], nv);
            nv = fmaf(v[1], v[1], nv);
            nv = fmaf(v[2], v[2], nv);
            nv = fmaf(v[3], v[3], nv);
        }
    }
    __syncthreads();
    float* gscr = qks;  // [16][624]
    const int wave = tid >> 6;
    if ((tid & 63) < 16) {
#pragma unroll
        for (int i = 0; i < 6; i++)
#pragma unroll
            for (int j = 0; j < 6; j++)
                gscr[wave * 624 + (tc * 6 + i) * 24 + (td * 6 + j)] = ga[i][j];
    }
    if (tid < 768) gscr[npg * 624 + 576 + nch] = nv;
    __syncthreads();
    if (tid < 624) {
        float s = 0.f;
#pragma unroll
        for (int w2 = 0; w2 < 16; w2++) s += gscr[w2 * 624 + tid];
        part[((size_t)(b * NHEADS + h) * 64 + stripe) * 624 + tid] = s;  // coalesced
    }
}

// ============ K34: reduce partials + attn + 4 top-k softmaxes -> A_eff ============
// part layout [bh][64 slots][624]; 32 stripes are real.
__global__ void k34_attn(const float* __restrict__ part, const float* __restrict__ temp,
                         const float* __restrict__ a1, const float* __restrict__ a2,
                         const float* __restrict__ a3, const float* __restrict__ a4,
                         float* __restrict__ Aeff) {
    __shared__ float gbuf[624];
    int bh = blockIdx.x;
    int h = bh & 7;
    int tid = threadIdx.x;
    for (int ti = tid; ti < 624; ti += 256) {
        float s = 0.f;
        const float* p = part + (size_t)bh * 64 * 624 + ti;
#pragma unroll 4
        for (int st = 0; st < 32; st++) s += p[st * 624];
        gbuf[ti] = s;
    }
    __syncthreads();
    int r = tid;
    if (r >= CDh) return;
    float t = temp[h];
    float aw[4] = {a1[0], a2[0], a3[0], a4[0]};
    const int kks[4] = {12, 16, 18, 19};
    float qn = fmaxf(sqrtf(gbuf[576 + r]), 1e-12f);
    float av[24];
    for (int d = 0; d < 24; d++) {
        float kn = fmaxf(sqrtf(gbuf[600 + d]), 1e-12f);
        av[d] = gbuf[r * 24 + d] / (qn * kn) * t;
    }
    int rank[24];
    float m = -1e30f;
    for (int d = 0; d < 24; d++) {
        int rk = 0;
        for (int e = 0; e < 24; e++)
            rk += (av[e] > av[d]) || (av[e] == av[d] && e < d);
        rank[d] = rk;
        m = fmaxf(m, av[d]);
    }
    float ex[24], outv[24];
    for (int d = 0; d < 24; d++) { ex[d] = expf(av[d] - m); outv[d] = 0.f; }
    for (int i = 0; i < 4; i++) {
        float Z = 0.f;
        for (int d = 0; d < 24; d++) if (rank[d] < kks[i]) Z += ex[d];
        float inv = aw[i] / Z;
        for (int d = 0; d < 24; d++) if (rank[d] < kks[i]) outv[d] += ex[d] * inv;
    }
    for (int d = 0; d < 24; d++) Aeff[(bh * 24 + r) * 24 + d] = outv[d];
}

// ============ K4b: M_b = W_proj @ blockdiag(A_eff) -> bf16 hi/lo ============
__global__ void k4b_mmat(const float* __restrict__ Wp, const float* __restrict__ Aeff,
                         ushort* __restrict__ Mh, ushort* __restrict__ Ml) {
    int b = blockIdx.x;
    int e0 = blockIdx.y * 6144;
    for (int e = e0 + threadIdx.x; e < e0 + 6144; e += 256) {
        int o = e / DIMC, j = e % DIMC;
        int h = j / CDh, d = j % CDh;
        const float* wrow = Wp + o * DIMC + h * CDh;
        const float* acol = Aeff + (size_t)((b * NHEADS + h) * CDh) * CDh + d;
        float s = 0.f;
        for (int c = 0; c < CDh; c++) s = fmaf(wrow[c], acol[c * CDh], s);
        size_t idx = ((size_t)b * DIMC + o) * DIMC + j;
        ushort hb = f2bf(s);
        Mh[idx] = hb;
        Ml[idx] = f2bf(s - bf2f(hb));
    }
}

extern "C" void kernel_launch(void* const* d_in, const int* in_sizes, int n_in,
                              void* d_out, int out_size, void* d_ws, size_t ws_size,
                              hipStream_t stream) {
    const float* x     = (const float*)d_in[0];
    const float* wqkv  = (const float*)d_in[1];
    const float* bqkv  = (const float*)d_in[2];
    const float* wdw   = (const float*)d_in[3];
    const float* bdw   = (const float*)d_in[4];
    const float* wproj = (const float*)d_in[5];
    const float* bproj = (const float*)d_in[6];
    const float* temp  = (const float*)d_in[7];
    const float* a1    = (const float*)d_in[8];
    const float* a2    = (const float*)d_in[9];
    const float* a3    = (const float*)d_in[10];
    const float* a4    = (const float*)d_in[11];
    float* out = (float*)d_out;

    float* ws = (float*)d_ws;
    const size_t fl_part = (size_t)64 * 64 * 624;
    const size_t fl_A    = (size_t)64 * 576;
    const size_t fl_M    = (size_t)NBATCH * DIMC * DIMC / 2;
    const size_t fl_W    = (size_t)C3 * DIMC / 2;
    const size_t fl_qkv1 = (size_t)C3 * HWN;
    const size_t base_fl = fl_part + fl_A + 2 * fl_M + 2 * fl_W;

    int nz = 1;
    if (ws_size >= (base_fl + 4 * fl_qkv1) * sizeof(float))      nz = 4;
    else if (ws_size >= (base_fl + 2 * fl_qkv1) * sizeof(float)) nz = 2;

    size_t o = 0;
    float* part = ws + o; o += fl_part;
    float* Aeff = ws + o; o += fl_A;
    ushort* Mh  = (ushort*)(ws + o); o += fl_M;
    ushort* Ml  = (ushort*)(ws + o); o += fl_M;
    ushort* Wh  = (ushort*)(ws + o); o += fl_W;
    ushort* Wl  = (ushort*)(ws + o); o += fl_W;
    float* qkv  = ws + o;

    const long qkv_zs = (long)fl_qkv1;

    k0_prep<<<(C3 * DIMC + 255) / 256, 256, 0, stream>>>(wqkv, Wh, Wl, C3 * DIMC);

    for (int b0 = 0; b0 < NBATCH; b0 += nz) {
        kgx3<<<dim3(256, 3, nz), 256, 0, stream>>>(x + (size_t)b0 * DIMC * HWN,
                                                   Wh, Wl, bqkv, qkv, qkv_zs);
        k2_dw<<<dim3(32, 8, nz), 1024, 0, stream>>>(qkv, qkv_zs, wdw, bdw, out, part, b0);
    }
    k34_attn<<<64, 256, 0, stream>>>(part, temp, a1, a2, a3, a4, Aeff);
    k4b_mmat<<<dim3(8, 6), 256, 0, stream>>>(wproj, Aeff, Mh, Ml);
    kg3f<<<dim3(256, 8), 256, 0, stream>>>(out, Mh, Ml, bproj);
}